// Round 3
// baseline (10007.769 us; speedup 1.0000x reference)
//
#include <hip/hip_runtime.h>
#include <math.h>
#include <stdint.h>

// Problem constants
#define DD 500
#define BB 512
// N layout (t>=1):  [r: x@(Wih_r+Whh_r) | z: x@(Wih_z+Whh_z) | i_n: x@Wih_n | h_n: x@Whh_n]
//   cols [0,500) r, [512,1012) z, [1024,1524) i_n, [1536,2036) h_n, pads zero-weighted.
// t=0 uses Wp0 whose r/z blocks are Wih only (h=0 -> gh contributes biases alone).
#define NW 2048        // padded N
#define NSTRIPS 64     // n-strips of 32
#define MSTRIPS 16     // m-strips of 32
#define KSTEPS  96     // ksteps of 16 (K = 1536: [Ah(512) | Al(512) | Ah(512)])
#define NELEM (BB*DD)
#define NBLK 256       // persistent grid: 1 block per CU by construction

typedef _Float16 f16;
typedef _Float16 f16x8 __attribute__((ext_vector_type(8)));
typedef float    f32x16 __attribute__((ext_vector_type(16)));

// Fragment-order layout (both Ap and Wp):
//   elem(strip, kstep, ln, j)  at  ((strip*KSTEPS + kstep)*64 + ln)*8 + j
//   maps to  row = strip*32 + (ln&31),  k = kstep*16 + (ln>>5)*8 + j
// which is exactly the mfma_f32_32x32x16_f16 A/B operand layout.

// ---------------------------------------------------------------------------
// Wp0 (t=0) and Wp1 (t>=1) in frag order. k-blocks of 512: [Wh | Wh | Wl].
// seg = n>>9: 0 -> r rows, 1 -> z rows, 2 -> i_n rows (Wih), 3 -> h_n rows (Whh).
// Wp0: seg0/1 = Wih only.  Wp1: seg0/1 = Wih + Whh.  seg2/3 identical in both.
// ---------------------------------------------------------------------------
__global__ __launch_bounds__(256) void conv_w(const float* __restrict__ Wih,
                                              const float* __restrict__ Whh,
                                              f16* __restrict__ Wp0,
                                              f16* __restrict__ Wp1)
{
    int p = blockIdx.x * 256 + threadIdx.x;    // (strip, kstep, ln)
    const int ln = p & 63; p >>= 6;
    const int kstep = p % KSTEPS;
    const int strip = p / KSTEPS;              // 0..63
    const int n = strip * 32 + (ln & 31);      // 0..2047
    const int kb0 = kstep * 16 + (ln >> 5) * 8;
    const int blk = kb0 >> 9, bk0 = kb0 & 511;
    const int seg = n >> 9;                    // 0..3
    const int dseg = n & 511;
    const float* pih = 0;
    const float* phh = 0;
    if (dseg < 500) {
        if (seg == 0)      { pih = Wih + (size_t)dseg * DD;
                             phh = Whh + (size_t)dseg * DD; }
        else if (seg == 1) { pih = Wih + (size_t)(500 + dseg) * DD;
                             phh = Whh + (size_t)(500 + dseg) * DD; }
        else if (seg == 2) { pih = Wih + (size_t)(1000 + dseg) * DD; }
        else               { phh = Whh + (size_t)(1000 + dseg) * DD; }
    }
    f16 o0[8], o1[8];
    #pragma unroll
    for (int j = 0; j < 8; ++j) {
        const int bk = bk0 + j;
        float vi = 0.f, vh = 0.f;
        if (bk < DD) {
            if (pih) vi = pih[bk];
            if (phh) vh = phh[bk];
        }
        const float v0 = (seg == 3) ? vh : vi;           // Wp0 value
        const float v1 = (seg <= 1) ? (vi + vh) : v0;    // Wp1 value
        f16 h0 = (f16)v0;
        f16 h1 = (f16)v1;
        o0[j] = (blk == 2) ? (f16)(v0 - (float)h0) : h0;
        o1[j] = (blk == 2) ? (f16)(v1 - (float)h1) : h1;
    }
    const size_t off = ((size_t)(strip * KSTEPS + kstep) * 64 + ln) * 8;
    *(uint4*)(Wp0 + off) = *(uint4*)o0;
    *(uint4*)(Wp1 + off) = *(uint4*)o1;
}

// ---------------------------------------------------------------------------
// Ap (frag order) from initial state. k-blocks: [Ah | Al | Ah]
// ---------------------------------------------------------------------------
__global__ __launch_bounds__(256) void conv_a(const float* __restrict__ S,
                                              f16* __restrict__ Ap)
{
    int p = blockIdx.x * 256 + threadIdx.x;    // (mstrip, kstep, ln)
    const int ln = p & 63; p >>= 6;
    const int kstep = p % KSTEPS;
    const int strip = p / KSTEPS;              // 0..15
    const int b = strip * 32 + (ln & 31);
    const int kb0 = kstep * 16 + (ln >> 5) * 8;
    const int blk = kb0 >> 9, bk0 = kb0 & 511;
    f16 out[8];
    #pragma unroll
    for (int j = 0; j < 8; ++j) {
        const int bk = bk0 + j;
        float v = (bk < DD) ? S[(size_t)b * DD + bk] : 0.f;
        f16 hi = (f16)v;
        out[j] = (blk == 1) ? (f16)(v - (float)hi) : hi;
    }
    *(uint4*)(Ap + ((size_t)(strip * KSTEPS + kstep) * 64 + ln) * 8) = *(uint4*)out;
}

// ---------------------------------------------------------------------------
// Device-wide two-level barrier, monotonic counters (no reset races).
// Layout (uints): bar[g*16] g=0..31 group counters (64B apart),
//                 bar[512] root counter, bar[528] generation.
// Episode e: group target 8*(e+1), root target 32*(e+1), gen -> e+1.
// All threads fence (release before arrive, acquire after wakeup) so data
// written before the barrier is visible across XCDs after it.
// ---------------------------------------------------------------------------
__device__ __forceinline__ void grid_sync(unsigned* bar, unsigned e)
{
    __threadfence();           // release: order this thread's prior stores
    __syncthreads();           // all block stores fenced before arrive
    if (threadIdx.x == 0) {
        unsigned* gcnt = bar + ((blockIdx.x >> 3) << 4);
        unsigned* root = bar + 512;
        unsigned* gen  = bar + 528;
        unsigned a = __hip_atomic_fetch_add(gcnt, 1u, __ATOMIC_ACQ_REL,
                                            __HIP_MEMORY_SCOPE_AGENT);
        if (a == e * 8u + 7u) {
            unsigned r = __hip_atomic_fetch_add(root, 1u, __ATOMIC_ACQ_REL,
                                                __HIP_MEMORY_SCOPE_AGENT);
            if (r == e * 32u + 31u) {
                __hip_atomic_store(gen, e + 1u, __ATOMIC_RELEASE,
                                   __HIP_MEMORY_SCOPE_AGENT);
            } else {
                while (__hip_atomic_load(gen, __ATOMIC_ACQUIRE,
                                         __HIP_MEMORY_SCOPE_AGENT) <= e)
                    __builtin_amdgcn_s_sleep(1);
            }
        } else {
            while (__hip_atomic_load(gen, __ATOMIC_ACQUIRE,
                                     __HIP_MEMORY_SCOPE_AGENT) <= e)
                __builtin_amdgcn_s_sleep(1);
        }
    }
    __syncthreads();
    __threadfence();           // acquire: invalidate stale cached lines
}

// ---------------------------------------------------------------------------
// Persistent fused kernel: 64 iterations of {GEMM phase | barrier | EW phase
// | barrier | break check} in a single NORMAL launch. 256 blocks x 256
// threads; every CU can host >=1 such block, so all blocks are co-resident
// and the spin barrier cannot deadlock.
//
// GEMM phase: bid -> (bm 0..3, bn 0..31, kh 0..1); block computes a 128x64
// tile of C[512x2048] over one K-half (48 ksteps) with 4 waves (2m x 2n),
// each wave a 64x32 tile, pure register streaming (16-deep rings, no LDS).
//
// EW phase: block bid handles rows 2*bid, 2*bid+1: gates, h update, Ap
// refresh (frag order), partial sum -> atomicAdd slots[t].
// ---------------------------------------------------------------------------
__global__ __launch_bounds__(256) void gru_persist(
    f16* __restrict__ Ap, const f16* __restrict__ Wp0,
    const f16* __restrict__ Wp1,
    float* __restrict__ C0, float* __restrict__ C1,
    const float* __restrict__ bih, const float* __restrict__ bhh,
    float* __restrict__ h, float* __restrict__ slots,
    const float* __restrict__ bc, const int* __restrict__ rec,
    unsigned* __restrict__ bar)
{
    const int bid = blockIdx.x;
    const int tid = threadIdx.x;
    const int rounds = min(64, rec[0]);
    const float thr = bc[0] * (float)NELEM;

    // gemm decomposition
    const int kh = bid & 1;
    const int bn = (bid >> 1) & 31;
    const int bm = bid >> 6;
    const int wv = tid >> 6, ln = tid & 63;
    const int wm = wv & 1;            // m half (64 rows = 2 m-strips)
    const int wn = wv >> 1;           // n strip within pair
    const int ks0 = kh * 48;
    float* __restrict__ Cw = kh ? C1 : C0;

    const size_t boff = ((size_t)((bn * 2 + wn) * KSTEPS + ks0) * 64 + ln) * 8;
    const f16* Ap0 = Ap + ((size_t)((bm * 4 + 2 * wm)     * KSTEPS + ks0) * 64 + ln) * 8;
    const f16* Ap1 = Ap + ((size_t)((bm * 4 + 2 * wm + 1) * KSTEPS + ks0) * 64 + ln) * 8;

    // epilogue constants: C/D layout col=lane&31, row=(r&3)+8*(r>>2)+4*(lane>>5)
    const int col = bn * 64 + wn * 32 + (ln & 31);
    const int rb0 = (bm * 4 + 2 * wm) * 32 + 4 * (ln >> 5);

    __shared__ float red[4];
    unsigned ep = 0;

    for (int t = 0; t < rounds; ++t) {
        // ---------------- GEMM phase ----------------
        const f16* Bp = ((t == 0) ? Wp0 : Wp1) + boff;

        uint4 rA0[16], rA1[16], rB[16];
        #pragma unroll
        for (int i = 0; i < 16; ++i) {
            rA0[i] = *(const uint4*)(Ap0 + (size_t)i * 512);
            rA1[i] = *(const uint4*)(Ap1 + (size_t)i * 512);
            rB[i]  = *(const uint4*)(Bp  + (size_t)i * 512);
        }
        f32x16 acc0 = {}, acc1 = {};
        #pragma unroll
        for (int ks = 0; ks < 48; ++ks) {
            const int sl = ks & 15;                // compile-time (full unroll)
            f16x8 a0 = *(f16x8*)&rA0[sl];
            f16x8 a1 = *(f16x8*)&rA1[sl];
            f16x8 b  = *(f16x8*)&rB[sl];
            acc0 = __builtin_amdgcn_mfma_f32_32x32x16_f16(a0, b, acc0, 0, 0, 0);
            acc1 = __builtin_amdgcn_mfma_f32_32x32x16_f16(a1, b, acc1, 0, 0, 0);
            if (ks < 32) {                         // refill 16 ksteps ahead
                rA0[sl] = *(const uint4*)(Ap0 + (size_t)(ks + 16) * 512);
                rA1[sl] = *(const uint4*)(Ap1 + (size_t)(ks + 16) * 512);
                rB[sl]  = *(const uint4*)(Bp  + (size_t)(ks + 16) * 512);
            }
        }
        #pragma unroll
        for (int r = 0; r < 16; ++r) {
            const int row = rb0 + (r & 3) + 8 * (r >> 2);
            Cw[(size_t)row * NW + col]        = acc0[r];
            Cw[(size_t)(row + 32) * NW + col] = acc1[r];
        }

        grid_sync(bar, ep++);      // C ready for all

        // ---------------- EW phase ----------------
        float psum = 0.0f;
        #pragma unroll
        for (int rr = 0; rr < 2; ++rr) {
            const int b = bid * 2 + rr;
            const float* Cb0 = C0 + (size_t)b * NW;
            const float* Cb1 = C1 + (size_t)b * NW;
            #pragma unroll
            for (int dp = 0; dp < 2; ++dp) {
                const int d = tid + dp * 256;
                if (d < DD) {
                    float cr  = Cb0[d]        + Cb1[d];
                    float cz  = Cb0[512 + d]  + Cb1[512 + d];
                    float cin = Cb0[1024 + d] + Cb1[1024 + d];
                    float r = 1.0f / (1.0f + expf(-(cr + bih[d] + bhh[d])));
                    float z = 1.0f / (1.0f + expf(-(cz + bih[500 + d] + bhh[500 + d])));
                    float inn = cin + bih[1000 + d];
                    float hn  = bhh[1000 + d];
                    float hp  = 0.0f;
                    if (t > 0) {   // at t=0 true h is 0; h_n column unused
                        hn += Cb0[1536 + d] + Cb1[1536 + d];
                        hp = h[b * DD + d];
                    }
                    float n = tanhf(inn + r * hn);
                    float hnew = (1.0f - z) * n + z * hp;
                    h[b * DD + d] = hnew;
                    psum += hnew;
                    // refresh Ap (frag order): k = d (hi), 512+d (lo), 1024+d (hi)
                    const int ms = b >> 5, lm = b & 31;
                    f16 hi = (f16)hnew;
                    f16 lo = (f16)(hnew - (float)hi);
                    {
                        int k = d, kstep = k >> 4, half = (k >> 3) & 1, j = k & 7;
                        Ap[((size_t)(ms * KSTEPS + kstep) * 64 + half * 32 + lm) * 8 + j] = hi;
                    }
                    {
                        int k = 512 + d, kstep = k >> 4, half = (k >> 3) & 1, j = k & 7;
                        Ap[((size_t)(ms * KSTEPS + kstep) * 64 + half * 32 + lm) * 8 + j] = lo;
                    }
                    {
                        int k = 1024 + d, kstep = k >> 4, half = (k >> 3) & 1, j = k & 7;
                        Ap[((size_t)(ms * KSTEPS + kstep) * 64 + half * 32 + lm) * 8 + j] = hi;
                    }
                }
            }
        }
        // block reduce psum -> slots[t]
        #pragma unroll
        for (int off = 32; off > 0; off >>= 1) psum += __shfl_down(psum, off, 64);
        if (ln == 0) red[wv] = psum;
        __syncthreads();
        if (tid == 0) atomicAdd(&slots[t], red[0] + red[1] + red[2] + red[3]);

        grid_sync(bar, ep++);      // slots[t] + Ap ready; C safe to overwrite

        // break check (uniform across grid): latch semantics of the reference
        float s = __hip_atomic_load(&slots[t], __ATOMIC_RELAXED,
                                    __HIP_MEMORY_SCOPE_AGENT);
        if (s > thr) break;
    }
}

extern "C" void kernel_launch(void* const* d_in, const int* in_sizes, int n_in,
                              void* d_out, int out_size, void* d_ws, size_t ws_size,
                              hipStream_t stream)
{
    const float* state = (const float*)d_in[0];
    const float* Wih   = (const float*)d_in[1];
    const float* Whh   = (const float*)d_in[2];
    const float* bih   = (const float*)d_in[3];
    const float* bhh   = (const float*)d_in[4];
    const float* bc    = (const float*)d_in[5];
    const int*   rec   = (const int*)d_in[6];

    char* ws = (char*)d_ws;
    float*    slots = (float*)ws;                                     // 256 B
    unsigned* bar   = (unsigned*)(ws + 256);                          // 4 KB
    f16*   Ap    = (f16*)(ws + 256 + 4096);                           // 1.57 MB
    f16*   Wp0   = Ap  + (size_t)MSTRIPS * KSTEPS * 64 * 8;           // 6.29 MB
    f16*   Wp1   = Wp0 + (size_t)NSTRIPS * KSTEPS * 64 * 8;           // 6.29 MB
    float* C0    = (float*)(Wp1 + (size_t)NSTRIPS * KSTEPS * 64 * 8); // 4.19 MB
    float* C1    = C0 + (size_t)BB * NW;                              // 4.19 MB
    float* out   = (float*)d_out;

    hipMemsetAsync(ws, 0, 256 + 4096, stream);   // slots + barrier state
    // rec==0 robustness: output = state if no iteration runs
    hipMemcpyAsync(out, state, (size_t)NELEM * sizeof(float),
                   hipMemcpyDeviceToDevice, stream);

    conv_w<<<dim3(NSTRIPS * KSTEPS * 64 / 256), 256, 0, stream>>>(Wih, Whh, Wp0, Wp1);
    conv_a<<<dim3(MSTRIPS * KSTEPS * 64 / 256), 256, 0, stream>>>(state, Ap);

    gru_persist<<<dim3(NBLK), dim3(256), 0, stream>>>(
        Ap, Wp0, Wp1, C0, C1, bih, bhh, out, slots, bc, rec, bar);
}

// Round 4
// 2628.198 us; speedup vs baseline: 3.8078x; 3.8078x over previous
//
#include <hip/hip_runtime.h>
#include <math.h>
#include <stdint.h>

// Problem constants
#define DD 500
#define BB 512
// N layout (t>=1):  [r: x@(Wih_r+Whh_r) | z: x@(Wih_z+Whh_z) | i_n: x@Wih_n | h_n: x@Whh_n]
//   cols [0,500) r, [512,1012) z, [1024,1524) i_n, [1536,2036) h_n, pads zero-weighted.
// t=0 uses Wp0 whose r/z blocks are Wih only (h=0 -> gh contributes biases alone).
#define NW 2048        // padded N
#define NSTRIPS 64     // n-strips of 32
#define MSTRIPS 16     // m-strips of 32
#define KSTEPS  96     // ksteps of 16 (K = 1536: [Ah(512) | Al(512) | Ah(512)])
#define NELEM (BB*DD)
#define NBLK 256       // persistent grid: co-resident by construction

typedef _Float16 f16;
typedef _Float16 f16x8 __attribute__((ext_vector_type(8)));
typedef float    f32x16 __attribute__((ext_vector_type(16)));

// Fragment-order layout (both Ap and Wp):
//   elem(strip, kstep, ln, j)  at  ((strip*KSTEPS + kstep)*64 + ln)*8 + j
//   maps to  row = strip*32 + (ln&31),  k = kstep*16 + (ln>>5)*8 + j
// which is exactly the mfma_f32_32x32x16_f16 A/B operand layout.

// ---------------------------------------------------------------------------
// Device-scope (cross-XCD coherent) access helpers. Relaxed atomics at AGENT
// scope compile to sc-flagged loads/stores that bypass the per-XCD L2 and are
// served at the device coherence point (Infinity Cache). No cache-wide
// maintenance ops (buffer_wbl2 / buffer_inv) are ever emitted.
// ---------------------------------------------------------------------------
__device__ __forceinline__ float aload_f32(const float* p) {
    return __hip_atomic_load(p, __ATOMIC_RELAXED, __HIP_MEMORY_SCOPE_AGENT);
}
__device__ __forceinline__ void astore_f32(float* p, float v) {
    __hip_atomic_store(p, v, __ATOMIC_RELAXED, __HIP_MEMORY_SCOPE_AGENT);
}
__device__ __forceinline__ void astore_u32(unsigned* p, unsigned v) {
    __hip_atomic_store(p, v, __ATOMIC_RELAXED, __HIP_MEMORY_SCOPE_AGENT);
}
__device__ __forceinline__ uint4 aload16(const f16* p) {   // 16B via 2x8B
    const unsigned long long* q = (const unsigned long long*)p;
    unsigned long long a = __hip_atomic_load(q,     __ATOMIC_RELAXED,
                                             __HIP_MEMORY_SCOPE_AGENT);
    unsigned long long b = __hip_atomic_load(q + 1, __ATOMIC_RELAXED,
                                             __HIP_MEMORY_SCOPE_AGENT);
    uint4 r;
    r.x = (unsigned)a;  r.y = (unsigned)(a >> 32);
    r.z = (unsigned)b;  r.w = (unsigned)(b >> 32);
    return r;
}

// ---------------------------------------------------------------------------
// Wp0 (t=0) and Wp1 (t>=1) in frag order. k-blocks of 512: [Wh | Wh | Wl].
// seg = n>>9: 0 -> r rows, 1 -> z rows, 2 -> i_n rows (Wih), 3 -> h_n rows (Whh).
// Wp0: seg0/1 = Wih only.  Wp1: seg0/1 = Wih + Whh.  seg2/3 identical in both.
// ---------------------------------------------------------------------------
__global__ __launch_bounds__(256) void conv_w(const float* __restrict__ Wih,
                                              const float* __restrict__ Whh,
                                              f16* __restrict__ Wp0,
                                              f16* __restrict__ Wp1)
{
    int p = blockIdx.x * 256 + threadIdx.x;    // (strip, kstep, ln)
    const int ln = p & 63; p >>= 6;
    const int kstep = p % KSTEPS;
    const int strip = p / KSTEPS;              // 0..63
    const int n = strip * 32 + (ln & 31);      // 0..2047
    const int kb0 = kstep * 16 + (ln >> 5) * 8;
    const int blk = kb0 >> 9, bk0 = kb0 & 511;
    const int seg = n >> 9;                    // 0..3
    const int dseg = n & 511;
    const float* pih = 0;
    const float* phh = 0;
    if (dseg < 500) {
        if (seg == 0)      { pih = Wih + (size_t)dseg * DD;
                             phh = Whh + (size_t)dseg * DD; }
        else if (seg == 1) { pih = Wih + (size_t)(500 + dseg) * DD;
                             phh = Whh + (size_t)(500 + dseg) * DD; }
        else if (seg == 2) { pih = Wih + (size_t)(1000 + dseg) * DD; }
        else               { phh = Whh + (size_t)(1000 + dseg) * DD; }
    }
    f16 o0[8], o1[8];
    #pragma unroll
    for (int j = 0; j < 8; ++j) {
        const int bk = bk0 + j;
        float vi = 0.f, vh = 0.f;
        if (bk < DD) {
            if (pih) vi = pih[bk];
            if (phh) vh = phh[bk];
        }
        const float v0 = (seg == 3) ? vh : vi;           // Wp0 value
        const float v1 = (seg <= 1) ? (vi + vh) : v0;    // Wp1 value
        f16 h0 = (f16)v0;
        f16 h1 = (f16)v1;
        o0[j] = (blk == 2) ? (f16)(v0 - (float)h0) : h0;
        o1[j] = (blk == 2) ? (f16)(v1 - (float)h1) : h1;
    }
    const size_t off = ((size_t)(strip * KSTEPS + kstep) * 64 + ln) * 8;
    *(uint4*)(Wp0 + off) = *(uint4*)o0;
    *(uint4*)(Wp1 + off) = *(uint4*)o1;
}

// ---------------------------------------------------------------------------
// Ap (frag order) from initial state. k-blocks: [Ah | Al | Ah]
// ---------------------------------------------------------------------------
__global__ __launch_bounds__(256) void conv_a(const float* __restrict__ S,
                                              f16* __restrict__ Ap)
{
    int p = blockIdx.x * 256 + threadIdx.x;    // (mstrip, kstep, ln)
    const int ln = p & 63; p >>= 6;
    const int kstep = p % KSTEPS;
    const int strip = p / KSTEPS;              // 0..15
    const int b = strip * 32 + (ln & 31);
    const int kb0 = kstep * 16 + (ln >> 5) * 8;
    const int blk = kb0 >> 9, bk0 = kb0 & 511;
    f16 out[8];
    #pragma unroll
    for (int j = 0; j < 8; ++j) {
        const int bk = bk0 + j;
        float v = (bk < DD) ? S[(size_t)b * DD + bk] : 0.f;
        f16 hi = (f16)v;
        out[j] = (blk == 1) ? (f16)(v - (float)hi) : hi;
    }
    *(uint4*)(Ap + ((size_t)(strip * KSTEPS + kstep) * 64 + ln) * 8) = *(uint4*)out;
}

// ---------------------------------------------------------------------------
// Device-wide two-level barrier, monotonic counters, RELAXED atomics only.
// Layout (uints): bar[g*16] g=0..31 group counters (64B apart),
//                 bar[512] root counter, bar[528] generation.
// Episode e: group target 8*(e+1), root target 32*(e+1), gen -> e+1.
// Visibility of data written before the barrier relies on device-scope
// (sc-flagged) stores acked from the coherence point before vmcnt retires;
// __syncthreads() emits s_waitcnt vmcnt(0) before s_barrier, so all of the
// block's coherent stores are globally visible before thread 0 arrives.
// No buffer_wbl2 / buffer_inv anywhere.
// ---------------------------------------------------------------------------
__device__ __forceinline__ void grid_sync(unsigned* bar, unsigned e)
{
    __syncthreads();
    if (threadIdx.x == 0) {
        unsigned* gcnt = bar + ((blockIdx.x >> 3) << 4);
        unsigned* root = bar + 512;
        unsigned* gen  = bar + 528;
        unsigned a = __hip_atomic_fetch_add(gcnt, 1u, __ATOMIC_RELAXED,
                                            __HIP_MEMORY_SCOPE_AGENT);
        if (a == e * 8u + 7u) {
            unsigned r = __hip_atomic_fetch_add(root, 1u, __ATOMIC_RELAXED,
                                                __HIP_MEMORY_SCOPE_AGENT);
            if (r == e * 32u + 31u) {
                __hip_atomic_store(gen, e + 1u, __ATOMIC_RELAXED,
                                   __HIP_MEMORY_SCOPE_AGENT);
            } else {
                while (__hip_atomic_load(gen, __ATOMIC_RELAXED,
                                         __HIP_MEMORY_SCOPE_AGENT) <= e)
                    __builtin_amdgcn_s_sleep(1);
            }
        } else {
            while (__hip_atomic_load(gen, __ATOMIC_RELAXED,
                                     __HIP_MEMORY_SCOPE_AGENT) <= e)
                __builtin_amdgcn_s_sleep(1);
        }
    }
    __syncthreads();
}

// ---------------------------------------------------------------------------
// Persistent fused kernel: 64 iterations of {GEMM phase | barrier | EW phase
// | barrier | break check} in a single normal launch. 256 blocks x 256
// threads; total residency capacity far exceeds the grid, so all blocks are
// co-resident and the spin barrier cannot deadlock.
//
// Coherence discipline:
//   Wp (weights)      : normal cached loads  -> L2-resident all 64 iters
//   h, biases, rec/bc : block-private / RO   -> normal cached
//   C, Ap, slots      : device-scope atomics -> served at Infinity Cache
// ---------------------------------------------------------------------------
__global__ __launch_bounds__(256) void gru_persist(
    f16* __restrict__ Ap, const f16* __restrict__ Wp0,
    const f16* __restrict__ Wp1,
    float* __restrict__ C0, float* __restrict__ C1,
    const float* __restrict__ bih, const float* __restrict__ bhh,
    float* __restrict__ h, float* __restrict__ slots,
    const float* __restrict__ bc, const int* __restrict__ rec,
    unsigned* __restrict__ bar)
{
    const int bid = blockIdx.x;
    const int tid = threadIdx.x;
    const int rounds = min(64, rec[0]);
    const float thr = bc[0] * (float)NELEM;

    // gemm decomposition
    const int kh = bid & 1;
    const int bn = (bid >> 1) & 31;
    const int bm = bid >> 6;
    const int wv = tid >> 6, ln = tid & 63;
    const int wm = wv & 1;            // m half (64 rows = 2 m-strips)
    const int wn = wv >> 1;           // n strip within pair
    const int ks0 = kh * 48;
    float* __restrict__ Cw = kh ? C1 : C0;

    const size_t boff = ((size_t)((bn * 2 + wn) * KSTEPS + ks0) * 64 + ln) * 8;
    const f16* Ap0 = Ap + ((size_t)((bm * 4 + 2 * wm)     * KSTEPS + ks0) * 64 + ln) * 8;
    const f16* Ap1 = Ap + ((size_t)((bm * 4 + 2 * wm + 1) * KSTEPS + ks0) * 64 + ln) * 8;

    // epilogue constants: C/D layout col=lane&31, row=(r&3)+8*(r>>2)+4*(lane>>5)
    const int col = bn * 64 + wn * 32 + (ln & 31);
    const int rb0 = (bm * 4 + 2 * wm) * 32 + 4 * (ln >> 5);

    __shared__ float red[4];
    unsigned ep = 0;

    for (int t = 0; t < rounds; ++t) {
        // ---------------- GEMM phase ----------------
        const f16* Bp = ((t == 0) ? Wp0 : Wp1) + boff;

        uint4 rA0[16], rA1[16], rB[16];
        #pragma unroll
        for (int i = 0; i < 16; ++i) {
            rA0[i] = aload16(Ap0 + (size_t)i * 512);
            rA1[i] = aload16(Ap1 + (size_t)i * 512);
            rB[i]  = *(const uint4*)(Bp + (size_t)i * 512);
        }
        f32x16 acc0 = {}, acc1 = {};
        #pragma unroll
        for (int ks = 0; ks < 48; ++ks) {
            const int sl = ks & 15;                // compile-time (full unroll)
            f16x8 a0 = *(f16x8*)&rA0[sl];
            f16x8 a1 = *(f16x8*)&rA1[sl];
            f16x8 b  = *(f16x8*)&rB[sl];
            acc0 = __builtin_amdgcn_mfma_f32_32x32x16_f16(a0, b, acc0, 0, 0, 0);
            acc1 = __builtin_amdgcn_mfma_f32_32x32x16_f16(a1, b, acc1, 0, 0, 0);
            if (ks < 32) {                         // refill 16 ksteps ahead
                rA0[sl] = aload16(Ap0 + (size_t)(ks + 16) * 512);
                rA1[sl] = aload16(Ap1 + (size_t)(ks + 16) * 512);
                rB[sl]  = *(const uint4*)(Bp + (size_t)(ks + 16) * 512);
            }
        }
        #pragma unroll
        for (int r = 0; r < 16; ++r) {
            const int row = rb0 + (r & 3) + 8 * (r >> 2);
            astore_f32(&Cw[(size_t)row * NW + col],        acc0[r]);
            astore_f32(&Cw[(size_t)(row + 32) * NW + col], acc1[r]);
        }

        grid_sync(bar, ep++);      // C globally visible

        // ---------------- EW phase ----------------
        float psum = 0.0f;
        #pragma unroll
        for (int rr = 0; rr < 2; ++rr) {
            const int b = bid * 2 + rr;
            const float* Cb0 = C0 + (size_t)b * NW;
            const float* Cb1 = C1 + (size_t)b * NW;
            #pragma unroll
            for (int dp = 0; dp < 2; ++dp) {
                const int d = tid + dp * 256;
                if (d < DD) {
                    float cr  = aload_f32(&Cb0[d])        + aload_f32(&Cb1[d]);
                    float cz  = aload_f32(&Cb0[512 + d])  + aload_f32(&Cb1[512 + d]);
                    float cin = aload_f32(&Cb0[1024 + d]) + aload_f32(&Cb1[1024 + d]);
                    float r = 1.0f / (1.0f + expf(-(cr + bih[d] + bhh[d])));
                    float z = 1.0f / (1.0f + expf(-(cz + bih[500 + d] + bhh[500 + d])));
                    float inn = cin + bih[1000 + d];
                    float hn  = bhh[1000 + d];
                    float hp  = 0.0f;
                    if (t > 0) {   // at t=0 true h is 0; h_n column unused
                        hn += aload_f32(&Cb0[1536 + d]) + aload_f32(&Cb1[1536 + d]);
                        hp = h[b * DD + d];
                    }
                    float n = tanhf(inn + r * hn);
                    float hnew = (1.0f - z) * n + z * hp;
                    h[b * DD + d] = hnew;      // block-private: normal store
                    psum += hnew;
                    // refresh Ap, dword-granular: even lane packs (d, d+1).
                    // k positions: d (hi), 512+d (lo), 1024+d (hi).
                    float hn1 = __shfl_down(hnew, 1, 64);
                    if ((tid & 1) == 0) {
                        const int ms = b >> 5, lm = b & 31;
                        f16 hi0 = (f16)hnew, lo0 = (f16)(hnew - (float)hi0);
                        f16 hi1 = (f16)hn1,  lo1 = (f16)(hn1  - (float)hi1);
                        unsigned hpack, lpack;
                        { union { f16 h; unsigned short u; } a, bb;
                          a.h = hi0; bb.h = hi1;
                          hpack = a.u | ((unsigned)bb.u << 16); }
                        { union { f16 h; unsigned short u; } a, bb;
                          a.h = lo0; bb.h = lo1;
                          lpack = a.u | ((unsigned)bb.u << 16); }
                        unsigned* Apd = (unsigned*)Ap;
                        #pragma unroll
                        for (int kk = 0; kk < 3; ++kk) {
                            const int k = d + kk * 512;     // kk=1 -> lo pack
                            const int kstep = k >> 4, half = (k >> 3) & 1, j = k & 7;
                            const size_t idx =
                                ((size_t)(ms * KSTEPS + kstep) * 64 + half * 32 + lm) * 8 + j;
                            astore_u32(Apd + (idx >> 1), (kk == 1) ? lpack : hpack);
                        }
                    }
                }
            }
        }
        // block reduce psum -> slots[t]
        #pragma unroll
        for (int off = 32; off > 0; off >>= 1) psum += __shfl_down(psum, off, 64);
        if (ln == 0) red[wv] = psum;
        __syncthreads();
        if (tid == 0)
            __hip_atomic_fetch_add(&slots[t], red[0] + red[1] + red[2] + red[3],
                                   __ATOMIC_RELAXED, __HIP_MEMORY_SCOPE_AGENT);

        grid_sync(bar, ep++);      // slots[t] + Ap globally visible

        // break check (uniform across grid): latch semantics of the reference
        float s = aload_f32(&slots[t]);
        if (s > thr) break;
    }
}

extern "C" void kernel_launch(void* const* d_in, const int* in_sizes, int n_in,
                              void* d_out, int out_size, void* d_ws, size_t ws_size,
                              hipStream_t stream)
{
    const float* state = (const float*)d_in[0];
    const float* Wih   = (const float*)d_in[1];
    const float* Whh   = (const float*)d_in[2];
    const float* bih   = (const float*)d_in[3];
    const float* bhh   = (const float*)d_in[4];
    const float* bc    = (const float*)d_in[5];
    const int*   rec   = (const int*)d_in[6];

    char* ws = (char*)d_ws;
    float*    slots = (float*)ws;                                     // 256 B
    unsigned* bar   = (unsigned*)(ws + 256);                          // 4 KB
    f16*   Ap    = (f16*)(ws + 256 + 4096);                           // 1.57 MB
    f16*   Wp0   = Ap  + (size_t)MSTRIPS * KSTEPS * 64 * 8;           // 6.29 MB
    f16*   Wp1   = Wp0 + (size_t)NSTRIPS * KSTEPS * 64 * 8;           // 6.29 MB
    float* C0    = (float*)(Wp1 + (size_t)NSTRIPS * KSTEPS * 64 * 8); // 4.19 MB
    float* C1    = C0 + (size_t)BB * NW;                              // 4.19 MB
    float* out   = (float*)d_out;

    hipMemsetAsync(ws, 0, 256 + 4096, stream);   // slots + barrier state
    // rec==0 robustness: output = state if no iteration runs
    hipMemcpyAsync(out, state, (size_t)NELEM * sizeof(float),
                   hipMemcpyDeviceToDevice, stream);

    conv_w<<<dim3(NSTRIPS * KSTEPS * 64 / 256), 256, 0, stream>>>(Wih, Whh, Wp0, Wp1);
    conv_a<<<dim3(MSTRIPS * KSTEPS * 64 / 256), 256, 0, stream>>>(state, Ap);

    gru_persist<<<dim3(NBLK), dim3(256), 0, stream>>>(
        Ap, Wp0, Wp1, C0, C1, bih, bhh, out, slots, bc, rec, bar);
}

// Round 5
// 1165.673 us; speedup vs baseline: 8.5854x; 2.2547x over previous
//
#include <hip/hip_runtime.h>
#include <math.h>
#include <stdint.h>

// Problem constants
#define DD 500
#define BB 512
// Permuted N layout: slab s (0..63) owns cols [32s, 32s+32) = [r|z|i_n|h_n]
// for d in [8s, 8s+8).  col 32s + 8g + dd  <->  gate g of d = 8s+dd.
// r/z cols hold x@(Wih+Whh) for t>=1 (x==h); t=0 uses Wp0 (Wih only in r/z).
// K = 1536 split-precision: [Ah(512) | Al(512) | Ah(512)] x [Wh | Wh | Wl].
#define NSTRIPS 64     // n-strips (slabs) of 32
#define MSTRIPS 16     // m-strips of 32
#define KSTEPS  96     // ksteps of 16
#define NELEM (BB*DD)
#define NBLK 256       // persistent grid: co-resident by construction

typedef _Float16 f16;
typedef _Float16 f16x8 __attribute__((ext_vector_type(8)));
typedef float    f32x16 __attribute__((ext_vector_type(16)));

#define APCNT ((size_t)MSTRIPS * KSTEPS * 64 * 8)   // f16 per Ap buffer
#define WPCNT ((size_t)NSTRIPS * KSTEPS * 64 * 8)   // f16 per Wp buffer

// Fragment-order layout (both Ap and Wp):
//   elem(strip, kstep, ln, j)  at  ((strip*KSTEPS + kstep)*64 + ln)*8 + j
//   maps to  row = strip*32 + (ln&31),  k = kstep*16 + (ln>>5)*8 + j
// which is exactly the mfma_f32_32x32x16_f16 A/B operand layout.

// ---------------------------------------------------------------------------
// Device-scope (cross-XCD coherent) access helpers: relaxed AGENT atomics.
// Proven correct + L2-friendly in round 4. No cache-wide maintenance ops.
// ---------------------------------------------------------------------------
__device__ __forceinline__ float aload_f32(const float* p) {
    return __hip_atomic_load(p, __ATOMIC_RELAXED, __HIP_MEMORY_SCOPE_AGENT);
}
__device__ __forceinline__ void astore_u64(unsigned long long* p,
                                           unsigned long long v) {
    __hip_atomic_store(p, v, __ATOMIC_RELAXED, __HIP_MEMORY_SCOPE_AGENT);
}
__device__ __forceinline__ uint4 aload16(const f16* p) {   // 16B via 2x8B
    const unsigned long long* q = (const unsigned long long*)p;
    unsigned long long a = __hip_atomic_load(q,     __ATOMIC_RELAXED,
                                             __HIP_MEMORY_SCOPE_AGENT);
    unsigned long long b = __hip_atomic_load(q + 1, __ATOMIC_RELAXED,
                                             __HIP_MEMORY_SCOPE_AGENT);
    uint4 r;
    r.x = (unsigned)a;  r.y = (unsigned)(a >> 32);
    r.z = (unsigned)b;  r.w = (unsigned)(b >> 32);
    return r;
}

// ---------------------------------------------------------------------------
// Wp0 (t=0) and Wp1 (t>=1), frag order, PERMUTED cols. k-blocks: [Wh|Wh|Wl].
// ---------------------------------------------------------------------------
__global__ __launch_bounds__(256) void conv_w(const float* __restrict__ Wih,
                                              const float* __restrict__ Whh,
                                              f16* __restrict__ Wp0,
                                              f16* __restrict__ Wp1)
{
    int p = blockIdx.x * 256 + threadIdx.x;    // (strip, kstep, ln)
    const int ln = p & 63; p >>= 6;
    const int kstep = p % KSTEPS;
    const int strip = p / KSTEPS;              // slab s, 0..63
    const int q = ln & 31;                     // col within slab
    const int g = q >> 3;                      // 0 r, 1 z, 2 i_n, 3 h_n
    const int d = strip * 8 + (q & 7);         // 0..511
    const int kb0 = kstep * 16 + (ln >> 5) * 8;
    const int blk = kb0 >> 9, bk0 = kb0 & 511;
    const float* pih = 0;
    const float* phh = 0;
    if (d < DD) {
        if (g == 0)      { pih = Wih + (size_t)d * DD;
                           phh = Whh + (size_t)d * DD; }
        else if (g == 1) { pih = Wih + (size_t)(500 + d) * DD;
                           phh = Whh + (size_t)(500 + d) * DD; }
        else if (g == 2) { pih = Wih + (size_t)(1000 + d) * DD; }
        else             { phh = Whh + (size_t)(1000 + d) * DD; }
    }
    f16 o0[8], o1[8];
    #pragma unroll
    for (int j = 0; j < 8; ++j) {
        const int bk = bk0 + j;
        float vi = 0.f, vh = 0.f;
        if (bk < DD) {
            if (pih) vi = pih[bk];
            if (phh) vh = phh[bk];
        }
        const float v0 = (g == 3) ? vh : vi;           // Wp0 value
        const float v1 = (g <= 1) ? (vi + vh) : v0;    // Wp1 value
        f16 h0 = (f16)v0;
        f16 h1 = (f16)v1;
        o0[j] = (blk == 2) ? (f16)(v0 - (float)h0) : h0;
        o1[j] = (blk == 2) ? (f16)(v1 - (float)h1) : h1;
    }
    const size_t off = ((size_t)(strip * KSTEPS + kstep) * 64 + ln) * 8;
    *(uint4*)(Wp0 + off) = *(uint4*)o0;
    *(uint4*)(Wp1 + off) = *(uint4*)o1;
}

// ---------------------------------------------------------------------------
// Ap buffer 0 (frag order) from initial state. k-blocks: [Ah | Al | Ah]
// ---------------------------------------------------------------------------
__global__ __launch_bounds__(256) void conv_a(const float* __restrict__ S,
                                              f16* __restrict__ Ap)
{
    int p = blockIdx.x * 256 + threadIdx.x;    // (mstrip, kstep, ln)
    const int ln = p & 63; p >>= 6;
    const int kstep = p % KSTEPS;
    const int strip = p / KSTEPS;              // 0..15
    const int b = strip * 32 + (ln & 31);
    const int kb0 = kstep * 16 + (ln >> 5) * 8;
    const int blk = kb0 >> 9, bk0 = kb0 & 511;
    f16 out[8];
    #pragma unroll
    for (int j = 0; j < 8; ++j) {
        const int bk = bk0 + j;
        float v = (bk < DD) ? S[(size_t)b * DD + bk] : 0.f;
        f16 hi = (f16)v;
        out[j] = (blk == 1) ? (f16)(v - (float)hi) : hi;
    }
    *(uint4*)(Ap + ((size_t)(strip * KSTEPS + kstep) * 64 + ln) * 8) = *(uint4*)out;
}

// ---------------------------------------------------------------------------
// Device-wide two-level barrier, monotonic counters, relaxed atomics only.
// bar[g*16] g=0..31 group counters (64B apart), bar[512] root, bar[528] gen.
// __syncthreads() (s_waitcnt vmcnt(0)) drains the block's device-scope
// stores before thread 0 arrives -> data visible after the barrier.
// ---------------------------------------------------------------------------
__device__ __forceinline__ void grid_sync(unsigned* bar, unsigned e)
{
    __syncthreads();
    if (threadIdx.x == 0) {
        unsigned* gcnt = bar + ((blockIdx.x >> 3) << 4);
        unsigned* root = bar + 512;
        unsigned* gen  = bar + 528;
        unsigned a = __hip_atomic_fetch_add(gcnt, 1u, __ATOMIC_RELAXED,
                                            __HIP_MEMORY_SCOPE_AGENT);
        if (a == e * 8u + 7u) {
            unsigned r = __hip_atomic_fetch_add(root, 1u, __ATOMIC_RELAXED,
                                                __HIP_MEMORY_SCOPE_AGENT);
            if (r == e * 32u + 31u) {
                __hip_atomic_store(gen, e + 1u, __ATOMIC_RELAXED,
                                   __HIP_MEMORY_SCOPE_AGENT);
            } else {
                while (__hip_atomic_load(gen, __ATOMIC_RELAXED,
                                         __HIP_MEMORY_SCOPE_AGENT) <= e)
                    __builtin_amdgcn_s_sleep(1);
            }
        } else {
            while (__hip_atomic_load(gen, __ATOMIC_RELAXED,
                                     __HIP_MEMORY_SCOPE_AGENT) <= e)
                __builtin_amdgcn_s_sleep(1);
        }
    }
    __syncthreads();
}

// ---------------------------------------------------------------------------
// Persistent fused kernel, ONE barrier per iteration.
// bid = mg*64 + s:  mg 0..3 (128 rows), s 0..63 (32-col slab, full K).
// Per iter: gemm 128x32xK=1536 (4 waves, 1 strip each, 96 MFMA, reg-stream,
// C -> LDS) | syncthreads | EW from LDS (gates, h in LDS, Ap pack to the
// triple-buffered Ap, slot shard add) | grid barrier | break check.
// Cross-block traffic per iter: Ap (1.5 MB) + 2 KB slots. C and h never
// leave the block.
// ---------------------------------------------------------------------------
__global__ __launch_bounds__(256, 1) void gru_persist(
    f16* __restrict__ ApB,                 // 3 buffers of APCNT
    const f16* __restrict__ Wp0, const f16* __restrict__ Wp1,
    const float* __restrict__ bih, const float* __restrict__ bhh,
    float* __restrict__ out, float* __restrict__ spart,  // [8][64] stride 64
    const float* __restrict__ bc, const int* __restrict__ rec,
    unsigned* __restrict__ bar)
{
    const int bid = blockIdx.x;
    const int tid = threadIdx.x;
    const int rounds = min(64, rec[0]);
    if (rounds <= 0) return;               // uniform: no barriers entered
    const float thr = bc[0] * (float)NELEM;

    const int s  = bid & 63;               // slab
    const int mg = bid >> 6;               // m-group (128 rows)
    const int wv = tid >> 6, ln = tid & 63;
    const int strip_m = mg * 4 + wv;       // this wave's m-strip

    const size_t aoff = (size_t)strip_m * KSTEPS * 512 + (size_t)ln * 8;
    const size_t boff = (size_t)s * KSTEPS * 512 + (size_t)ln * 8;

    f16* b0 = ApB;                         // gemm(t) reads b0
    f16* b1 = ApB + APCNT;                 // EW(t) writes b1
    f16* b2 = ApB + 2 * APCNT;

    __shared__ float Ct[128][33];          // C tile, +1 pad
    __shared__ float hbuf[128][8];         // block-owned h slice
    __shared__ float red[4];

    for (int t = 0; t < rounds; ++t) {
        // ---------------- GEMM phase (full K, one 32-col slab) ------------
        const f16* Bp  = ((t == 0) ? Wp0 : Wp1) + boff;
        const f16* Apb = b0 + aoff;

        uint4 rA[16], rB[16];
        #pragma unroll
        for (int i = 0; i < 16; ++i) {
            rA[i] = aload16(Apb + (size_t)i * 512);
            rB[i] = *(const uint4*)(Bp + (size_t)i * 512);
        }
        f32x16 ae = {}, ao = {};
        #pragma unroll
        for (int ks = 0; ks < 96; ++ks) {
            const int sl = ks & 15;            // compile-time (full unroll)
            f16x8 a = *(f16x8*)&rA[sl];
            f16x8 b = *(f16x8*)&rB[sl];
            if (ks & 1) ao = __builtin_amdgcn_mfma_f32_32x32x16_f16(a, b, ao, 0, 0, 0);
            else        ae = __builtin_amdgcn_mfma_f32_32x32x16_f16(a, b, ae, 0, 0, 0);
            if (ks < 80) {                     // refill 16 ksteps ahead
                rA[sl] = aload16(Apb + (size_t)(ks + 16) * 512);
                rB[sl] = *(const uint4*)(Bp + (size_t)(ks + 16) * 512);
            }
        }
        // C/D layout: col=lane&31, row=(r&3)+8*(r>>2)+4*(lane>>5)
        #pragma unroll
        for (int r = 0; r < 16; ++r) {
            const int rl = wv * 32 + (r & 3) + 8 * (r >> 2) + 4 * (ln >> 5);
            Ct[rl][ln & 31] = ae[r] + ao[r];
        }
        __syncthreads();

        // ---------------- EW phase (all in-block) -------------------------
        float psum = 0.0f;
        #pragma unroll
        for (int i = 0; i < 4; ++i) {
            const int p   = tid + 256 * i;     // 1024 (row, dd) pairs
            const int row = p >> 3, dd = p & 7;
            const int d   = s * 8 + dd;
            float hnew = 0.0f;
            if (d < DD) {
                float cr  = Ct[row][dd];
                float cz  = Ct[row][8 + dd];
                float cin = Ct[row][16 + dd];
                float chn = Ct[row][24 + dd];
                float r = 1.0f / (1.0f + expf(-(cr + bih[d] + bhh[d])));
                float z = 1.0f / (1.0f + expf(-(cz + bih[500 + d] + bhh[500 + d])));
                float inn = cin + bih[1000 + d];
                float hn  = bhh[1000 + d];
                float hp  = 0.0f;
                if (t > 0) { hn += chn; hp = hbuf[row][dd]; }
                float n = tanhf(inn + r * hn);
                hnew = (1.0f - z) * n + z * hp;
                psum += hnew;
            }
            hbuf[row][dd] = hnew;              // same-thread slot: race-free
        }
        // block reduce psum -> spart shard (8 lines, 32 RMWs each)
        #pragma unroll
        for (int off = 32; off > 0; off >>= 1) psum += __shfl_down(psum, off, 64);
        if (ln == 0) red[wv] = psum;
        __syncthreads();                        // also orders hbuf before pack
        if (tid == 0) {
            float v = red[0] + red[1] + red[2] + red[3];
            __hip_atomic_fetch_add(&spart[(size_t)(s & 7) * 64 + t], v,
                                   __ATOMIC_RELAXED, __HIP_MEMORY_SCOPE_AGENT);
        }
        // pack Ap rows (16B hi @k=8s, lo @k=512+8s, hi @k=1024+8s)
        if (tid < 128) {
            const int row = tid;
            const int strip = mg * 4 + (row >> 5), lm = row & 31;
            union { f16 a[8]; unsigned long long u[2]; } hiU, loU;
            #pragma unroll
            for (int j = 0; j < 8; ++j) {
                float v = hbuf[row][j];
                f16 hi = (f16)v;
                hiU.a[j] = hi;
                loU.a[j] = (f16)(v - (float)hi);
            }
            const int ksb = s >> 1, half = s & 1;
            const size_t i0 = ((size_t)(strip * KSTEPS + ksb)      * 64 + half * 32 + lm) * 8;
            const size_t i1 = ((size_t)(strip * KSTEPS + 32 + ksb) * 64 + half * 32 + lm) * 8;
            const size_t i2 = ((size_t)(strip * KSTEPS + 64 + ksb) * 64 + half * 32 + lm) * 8;
            astore_u64((unsigned long long*)(b1 + i0),     hiU.u[0]);
            astore_u64((unsigned long long*)(b1 + i0) + 1, hiU.u[1]);
            astore_u64((unsigned long long*)(b1 + i1),     loU.u[0]);
            astore_u64((unsigned long long*)(b1 + i1) + 1, loU.u[1]);
            astore_u64((unsigned long long*)(b1 + i2),     hiU.u[0]);
            astore_u64((unsigned long long*)(b1 + i2) + 1, hiU.u[1]);
        }

        grid_sync(bar, (unsigned)t);   // Ap(b1) + spart globally visible

        // break check (uniform): latch semantics of the reference
        float st = 0.0f;
        #pragma unroll
        for (int p8 = 0; p8 < 8; ++p8)
            st += aload_f32(&spart[(size_t)p8 * 64 + t]);
        if (st > thr) break;

        f16* tt = b0; b0 = b1; b1 = b2; b2 = tt;   // rotate triple buffer
    }

    // final output from block-owned h slice
    #pragma unroll
    for (int i = 0; i < 4; ++i) {
        const int p   = tid + 256 * i;
        const int row = p >> 3, dd = p & 7;
        const int d   = s * 8 + dd;
        if (d < DD)
            out[(size_t)(mg * 128 + row) * DD + d] = hbuf[row][dd];
    }
}

extern "C" void kernel_launch(void* const* d_in, const int* in_sizes, int n_in,
                              void* d_out, int out_size, void* d_ws, size_t ws_size,
                              hipStream_t stream)
{
    const float* state = (const float*)d_in[0];
    const float* Wih   = (const float*)d_in[1];
    const float* Whh   = (const float*)d_in[2];
    const float* bih   = (const float*)d_in[3];
    const float* bhh   = (const float*)d_in[4];
    const float* bc    = (const float*)d_in[5];
    const int*   rec   = (const int*)d_in[6];

    char* ws = (char*)d_ws;
    float*    spart = (float*)ws;                   // 2 KB (8 shards x 64 t)
    unsigned* bar   = (unsigned*)(ws + 2048);       // 4 KB
    f16*   ApB   = (f16*)(ws + 2048 + 4096);        // 3 x 1.57 MB
    f16*   Wp0   = ApB + 3 * APCNT;                 // 6.29 MB
    f16*   Wp1   = Wp0 + WPCNT;                     // 6.29 MB
    float* out   = (float*)d_out;

    hipMemsetAsync(ws, 0, 2048 + 4096, stream);     // spart + barrier state
    // rec==0 robustness: output = state if no iteration runs
    hipMemcpyAsync(out, state, (size_t)NELEM * sizeof(float),
                   hipMemcpyDeviceToDevice, stream);

    conv_w<<<dim3(NSTRIPS * KSTEPS * 64 / 256), 256, 0, stream>>>(Wih, Whh, Wp0, Wp1);
    conv_a<<<dim3(MSTRIPS * KSTEPS * 64 / 256), 256, 0, stream>>>(state, ApB);

    gru_persist<<<dim3(NBLK), dim3(256), 0, stream>>>(
        ApB, Wp0, Wp1, bih, bhh, out, spart, bc, rec, bar);
}

// Round 6
// 1099.966 us; speedup vs baseline: 9.0983x; 1.0597x over previous
//
#include <hip/hip_runtime.h>
#include <math.h>
#include <stdint.h>

// Problem constants
#define DD 500
#define BB 512
// Permuted N layout: slab s (0..63) owns cols [32s, 32s+32) = [r|z|i_n|h_n]
// for d in [8s, 8s+8).  col 32s + 8g + dd  <->  gate g of d = 8s+dd.
// r/z cols hold x@(Wih+Whh) for t>=1 (x==h); t=0 uses Wp0 (Wih only in r/z).
// K = 1536 split-precision: [Ah(512) | Al(512) | Ah(512)] x [Wh | Wh | Wl].
#define NSTRIPS 64     // n-strips (slabs) of 32
#define MSTRIPS 16     // m-strips of 32
#define KSTEPS  96     // ksteps of 16
#define NELEM (BB*DD)
// Persistent grid: 16 row-groups x 8 col-groups = 128 blocks.
// Block = 32 rows x 256 cols (8 slabs) x full K. bid%8 = col-group (= XCD
// under round-robin dispatch -> each XCD's L2 serves ONE 786KB Wp slice).
#define GM 16
#define GN 8
#define NBLK 128

typedef _Float16 f16;
typedef _Float16 f16x8 __attribute__((ext_vector_type(8)));
typedef float    f32x16 __attribute__((ext_vector_type(16)));

#define APCNT ((size_t)MSTRIPS * KSTEPS * 64 * 8)   // f16 per Ap buffer
#define WPCNT ((size_t)NSTRIPS * KSTEPS * 64 * 8)   // f16 per Wp buffer

// Fragment-order layout (both Ap and Wp):
//   elem(strip, kstep, ln, j)  at  ((strip*KSTEPS + kstep)*64 + ln)*8 + j
//   maps to  row = strip*32 + (ln&31),  k = kstep*16 + (ln>>5)*8 + j
// which is exactly the mfma_f32_32x32x16_f16 A/B operand layout.

// ---------------------------------------------------------------------------
// Device-scope (cross-XCD coherent) access helpers: relaxed AGENT atomics.
// sc-flagged, served at the Infinity Cache; no cache-wide maintenance ops.
// ---------------------------------------------------------------------------
__device__ __forceinline__ float aload_f32(const float* p) {
    return __hip_atomic_load(p, __ATOMIC_RELAXED, __HIP_MEMORY_SCOPE_AGENT);
}
__device__ __forceinline__ void astore_u64(unsigned long long* p,
                                           unsigned long long v) {
    __hip_atomic_store(p, v, __ATOMIC_RELAXED, __HIP_MEMORY_SCOPE_AGENT);
}
__device__ __forceinline__ uint4 aload16(const f16* p) {   // 16B via 2x8B
    const unsigned long long* q = (const unsigned long long*)p;
    unsigned long long a = __hip_atomic_load(q,     __ATOMIC_RELAXED,
                                             __HIP_MEMORY_SCOPE_AGENT);
    unsigned long long b = __hip_atomic_load(q + 1, __ATOMIC_RELAXED,
                                             __HIP_MEMORY_SCOPE_AGENT);
    uint4 r;
    r.x = (unsigned)a;  r.y = (unsigned)(a >> 32);
    r.z = (unsigned)b;  r.w = (unsigned)(b >> 32);
    return r;
}

// ---------------------------------------------------------------------------
// Wp0 (t=0) and Wp1 (t>=1), frag order, PERMUTED cols. k-blocks: [Wh|Wh|Wl].
// ---------------------------------------------------------------------------
__global__ __launch_bounds__(256) void conv_w(const float* __restrict__ Wih,
                                              const float* __restrict__ Whh,
                                              f16* __restrict__ Wp0,
                                              f16* __restrict__ Wp1)
{
    int p = blockIdx.x * 256 + threadIdx.x;    // (strip, kstep, ln)
    const int ln = p & 63; p >>= 6;
    const int kstep = p % KSTEPS;
    const int strip = p / KSTEPS;              // slab s, 0..63
    const int q = ln & 31;                     // col within slab
    const int g = q >> 3;                      // 0 r, 1 z, 2 i_n, 3 h_n
    const int d = strip * 8 + (q & 7);         // 0..511
    const int kb0 = kstep * 16 + (ln >> 5) * 8;
    const int blk = kb0 >> 9, bk0 = kb0 & 511;
    const float* pih = 0;
    const float* phh = 0;
    if (d < DD) {
        if (g == 0)      { pih = Wih + (size_t)d * DD;
                           phh = Whh + (size_t)d * DD; }
        else if (g == 1) { pih = Wih + (size_t)(500 + d) * DD;
                           phh = Whh + (size_t)(500 + d) * DD; }
        else if (g == 2) { pih = Wih + (size_t)(1000 + d) * DD; }
        else             { phh = Whh + (size_t)(1000 + d) * DD; }
    }
    f16 o0[8], o1[8];
    #pragma unroll
    for (int j = 0; j < 8; ++j) {
        const int bk = bk0 + j;
        float vi = 0.f, vh = 0.f;
        if (bk < DD) {
            if (pih) vi = pih[bk];
            if (phh) vh = phh[bk];
        }
        const float v0 = (g == 3) ? vh : vi;           // Wp0 value
        const float v1 = (g <= 1) ? (vi + vh) : v0;    // Wp1 value
        f16 h0 = (f16)v0;
        f16 h1 = (f16)v1;
        o0[j] = (blk == 2) ? (f16)(v0 - (float)h0) : h0;
        o1[j] = (blk == 2) ? (f16)(v1 - (float)h1) : h1;
    }
    const size_t off = ((size_t)(strip * KSTEPS + kstep) * 64 + ln) * 8;
    *(uint4*)(Wp0 + off) = *(uint4*)o0;
    *(uint4*)(Wp1 + off) = *(uint4*)o1;
}

// ---------------------------------------------------------------------------
// Ap buffer 0 (frag order) from initial state. k-blocks: [Ah | Al | Ah]
// ---------------------------------------------------------------------------
__global__ __launch_bounds__(256) void conv_a(const float* __restrict__ S,
                                              f16* __restrict__ Ap)
{
    int p = blockIdx.x * 256 + threadIdx.x;    // (mstrip, kstep, ln)
    const int ln = p & 63; p >>= 6;
    const int kstep = p % KSTEPS;
    const int strip = p / KSTEPS;              // 0..15
    const int b = strip * 32 + (ln & 31);
    const int kb0 = kstep * 16 + (ln >> 5) * 8;
    const int blk = kb0 >> 9, bk0 = kb0 & 511;
    f16 out[8];
    #pragma unroll
    for (int j = 0; j < 8; ++j) {
        const int bk = bk0 + j;
        float v = (bk < DD) ? S[(size_t)b * DD + bk] : 0.f;
        f16 hi = (f16)v;
        out[j] = (blk == 1) ? (f16)(v - (float)hi) : hi;
    }
    *(uint4*)(Ap + ((size_t)(strip * KSTEPS + kstep) * 64 + ln) * 8) = *(uint4*)out;
}

// ---------------------------------------------------------------------------
// Device-wide two-level barrier, monotonic counters, relaxed atomics only.
// bar[g*16] g=0..15 group counters (64B apart, 8 blocks each), bar[512] root
// (16 arrivals), bar[528] generation.  __syncthreads() (s_waitcnt vmcnt(0))
// drains the block's device-scope stores before thread 0 arrives.
// ---------------------------------------------------------------------------
__device__ __forceinline__ void grid_sync(unsigned* bar, unsigned e)
{
    __syncthreads();
    if (threadIdx.x == 0) {
        unsigned* gcnt = bar + ((blockIdx.x >> 3) << 4);
        unsigned* root = bar + 512;
        unsigned* gen  = bar + 528;
        unsigned a = __hip_atomic_fetch_add(gcnt, 1u, __ATOMIC_RELAXED,
                                            __HIP_MEMORY_SCOPE_AGENT);
        if (a == e * 8u + 7u) {
            unsigned r = __hip_atomic_fetch_add(root, 1u, __ATOMIC_RELAXED,
                                                __HIP_MEMORY_SCOPE_AGENT);
            if (r == e * 16u + 15u) {
                __hip_atomic_store(gen, e + 1u, __ATOMIC_RELAXED,
                                   __HIP_MEMORY_SCOPE_AGENT);
            } else {
                while (__hip_atomic_load(gen, __ATOMIC_RELAXED,
                                         __HIP_MEMORY_SCOPE_AGENT) <= e)
                    __builtin_amdgcn_s_sleep(1);
            }
        } else {
            while (__hip_atomic_load(gen, __ATOMIC_RELAXED,
                                     __HIP_MEMORY_SCOPE_AGENT) <= e)
                __builtin_amdgcn_s_sleep(1);
        }
    }
    __syncthreads();
}

// ---------------------------------------------------------------------------
// Persistent fused kernel, one grid barrier per iteration. 128 blocks x 256.
// bid = mg*8 + cg: block owns rows [32mg,32mg+32) x slabs [8cg, 8cg+8)
// (d in [64cg, 64cg+64)), full K.
// Per iter: stage A-slice (96 KB, contiguous frag-order, sc1) into a 2x24KB
// LDS double buffer in quarters overlapped with the MFMA sweep; 4 waves x
// 2 slabs each, B streamed from L2 (normal loads, XCD-resident); C -> LDS
// (Ct aliases the A buffers, padded layout); EW + h (LDS-persistent) + Ap
// pack (sc1, 12 KB) | grid barrier | break check.
// Cross-block traffic per iter: A-stage 12.3 MB + Ap 1.5 MB + 2 KB slots.
// ---------------------------------------------------------------------------
__global__ __launch_bounds__(256, 1) void gru_persist(
    f16* __restrict__ ApB,                 // 3 buffers of APCNT
    const f16* __restrict__ Wp0, const f16* __restrict__ Wp1,
    const float* __restrict__ bih, const float* __restrict__ bhh,
    float* __restrict__ out, float* __restrict__ spart,  // [8][64] stride 64
    const float* __restrict__ bc, const int* __restrict__ rec,
    unsigned* __restrict__ bar)
{
    const int bid = blockIdx.x;
    const int tid = threadIdx.x;
    const int rounds = min(64, rec[0]);
    if (rounds <= 0) return;               // uniform: no barriers entered
    const float thr = bc[0] * (float)NELEM;

    const int cg = bid & 7;                // col-group (d base = 64*cg)
    const int mg = bid >> 3;               // row-group = m-strip 0..15
    const int wv = tid >> 6, ln = tid & 63;
    const int sl0 = 2 * wv, sl1 = 2 * wv + 1;          // local slabs
    const int sb0 = cg * 8 + sl0, sb1 = sb0 + 1;       // global slabs

    // 48 KB region: A double-buffer (2 x 24 KB) during gemm, Ct (36 KB) after
    __shared__ __align__(16) char smem[49152];
    f16*   Abuf0 = (f16*)smem;
    f16*   Abuf1 = (f16*)(smem + 24576);
    float* Ct    = (float*)smem;           // [row][sl][g][dd] = [32][8][4][9]
    __shared__ float hbuf[32 * 65];        // block-owned h, +1 pad
    __shared__ float red[4];

    f16* b0 = ApB;                         // gemm(t) reads b0
    f16* b1 = ApB + APCNT;                 // EW(t) writes b1
    f16* b2 = ApB + 2 * APCNT;

    for (int t = 0; t < rounds; ++t) {
        const f16* Wb  = (t == 0) ? Wp0 : Wp1;
        const f16* Bp0 = Wb + (size_t)sb0 * KSTEPS * 512 + (size_t)ln * 8;
        const f16* Bp1 = Wb + (size_t)sb1 * KSTEPS * 512 + (size_t)ln * 8;
        const f16* Asrc = b0 + (size_t)mg * KSTEPS * 512;   // 96 KB contig

        // B register rings (L2-resident, normal loads)
        uint4 rB0[8], rB1[8];
        #pragma unroll
        for (int i = 0; i < 8; ++i) {
            rB0[i] = *(const uint4*)(Bp0 + (size_t)i * 512);
            rB1[i] = *(const uint4*)(Bp1 + (size_t)i * 512);
        }
        // stage quarter 0 (24 KB = 6 x uint4 per thread)
        {
            uint4 s[6];
            #pragma unroll
            for (int i = 0; i < 6; ++i)
                s[i] = aload16(Asrc + (size_t)(tid + 256 * i) * 8);
            #pragma unroll
            for (int i = 0; i < 6; ++i)
                *(uint4*)(Abuf0 + (size_t)(tid + 256 * i) * 8) = s[i];
            __syncthreads();
        }
        f32x16 acc0 = {}, acc1 = {};
        #pragma unroll
        for (int kq = 0; kq < 4; ++kq) {
            uint4 s[6];
            if (kq < 3) {                  // issue next-quarter loads early
                #pragma unroll
                for (int i = 0; i < 6; ++i)
                    s[i] = aload16(Asrc + (size_t)(kq + 1) * 24 * 512
                                        + (size_t)(tid + 256 * i) * 8);
            }
            const f16* Ab = (kq & 1) ? Abuf1 : Abuf0;
            #pragma unroll
            for (int k2 = 0; k2 < 24; ++k2) {
                const int ks = kq * 24 + k2;
                f16x8 a  = *(const f16x8*)(Ab + (size_t)(k2 * 64 + ln) * 8);
                f16x8 bb0 = *(f16x8*)&rB0[ks & 7];
                f16x8 bb1 = *(f16x8*)&rB1[ks & 7];
                acc0 = __builtin_amdgcn_mfma_f32_32x32x16_f16(a, bb0, acc0, 0, 0, 0);
                acc1 = __builtin_amdgcn_mfma_f32_32x32x16_f16(a, bb1, acc1, 0, 0, 0);
                if (ks < 88) {             // refill 8 ksteps ahead
                    rB0[ks & 7] = *(const uint4*)(Bp0 + (size_t)(ks + 8) * 512);
                    rB1[ks & 7] = *(const uint4*)(Bp1 + (size_t)(ks + 8) * 512);
                }
            }
            if (kq < 3) {
                f16* Aw = (kq & 1) ? Abuf0 : Abuf1;
                #pragma unroll
                for (int i = 0; i < 6; ++i)
                    *(uint4*)(Aw + (size_t)(tid + 256 * i) * 8) = s[i];
            }
            __syncthreads();
        }
        // C -> LDS. C/D layout: col=lane&31, row=(r&3)+8*(r>>2)+4*(lane>>5).
        // Ct addr = row*288 + sl*36 + g*9 + dd  (<=2-way banks)
        {
            const int q = ln & 31, g = q >> 3, dd = q & 7;
            #pragma unroll
            for (int r = 0; r < 16; ++r) {
                const int row = (r & 3) + 8 * (r >> 2) + 4 * (ln >> 5);
                Ct[row * 288 + sl0 * 36 + g * 9 + dd] = acc0[r];
                Ct[row * 288 + sl1 * 36 + g * 9 + dd] = acc1[r];
            }
        }
        __syncthreads();

        // ---------------- EW phase (all in-block) -------------------------
        float psum = 0.0f;
        #pragma unroll
        for (int i = 0; i < 8; ++i) {
            const int idx = i * 256 + tid;     // 2048 (row, dl) pairs
            const int row = idx >> 6, dl = idx & 63;
            const int d = cg * 64 + dl;
            const int sl = dl >> 3, dd = dl & 7;
            float hnew = 0.0f;
            if (d < DD) {
                const float* cb = &Ct[row * 288 + sl * 36 + dd];
                float cr = cb[0], cz = cb[9], cin = cb[18], chn = cb[27];
                float r = 1.0f / (1.0f + expf(-(cr + bih[d] + bhh[d])));
                float z = 1.0f / (1.0f + expf(-(cz + bih[500 + d] + bhh[500 + d])));
                float inn = cin + bih[1000 + d];
                float hn  = bhh[1000 + d];
                float hp  = 0.0f;
                if (t > 0) { hn += chn; hp = hbuf[row * 65 + dl]; }
                float n = tanhf(inn + r * hn);
                hnew = (1.0f - z) * n + z * hp;
                psum += hnew;
            }
            hbuf[row * 65 + dl] = hnew;        // same-thread slot: race-free
        }
        // block reduce psum -> spart shard cg (16 adders per shard line)
        #pragma unroll
        for (int off = 32; off > 0; off >>= 1) psum += __shfl_down(psum, off, 64);
        if (ln == 0) red[wv] = psum;
        __syncthreads();                        // also orders hbuf before pack
        if (tid == 0) {
            float v = red[0] + red[1] + red[2] + red[3];
            __hip_atomic_fetch_add(&spart[(size_t)cg * 64 + t], v,
                                   __ATOMIC_RELAXED, __HIP_MEMORY_SCOPE_AGENT);
        }
        // pack Ap (16B per (row, d-octet, k-block)): hi @k=d, lo @512+d, hi @1024+d
        {
            const int lm = tid & 31, oct = tid >> 5;   // row, d-octet
            union { f16 a[8]; unsigned long long u[2]; } hiU, loU;
            #pragma unroll
            for (int j = 0; j < 8; ++j) {
                float v = hbuf[lm * 65 + oct * 8 + j];
                f16 hi = (f16)v;
                hiU.a[j] = hi;
                loU.a[j] = (f16)(v - (float)hi);
            }
            const int d0 = cg * 64 + oct * 8;
            #pragma unroll
            for (int kb = 0; kb < 3; ++kb) {
                const int k0 = kb * 512 + d0;
                const int kstep = k0 >> 4, half = (k0 >> 3) & 1;
                unsigned long long* dst = (unsigned long long*)
                    (b1 + ((size_t)(mg * KSTEPS + kstep) * 64 + half * 32 + lm) * 8);
                astore_u64(dst,     (kb == 1) ? loU.u[0] : hiU.u[0]);
                astore_u64(dst + 1, (kb == 1) ? loU.u[1] : hiU.u[1]);
            }
        }

        grid_sync(bar, (unsigned)t);   // Ap(b1) + spart globally visible

        // break check (uniform): latch semantics of the reference
        float st = 0.0f;
        #pragma unroll
        for (int p8 = 0; p8 < 8; ++p8)
            st += aload_f32(&spart[(size_t)p8 * 64 + t]);
        if (st > thr) break;

        f16* tt = b0; b0 = b1; b1 = b2; b2 = tt;   // rotate triple buffer
    }

    // final output from block-owned h slice
    #pragma unroll
    for (int i = 0; i < 8; ++i) {
        const int idx = i * 256 + tid;
        const int row = idx >> 6, dl = idx & 63;
        const int d = cg * 64 + dl;
        if (d < DD)
            out[(size_t)(mg * 32 + row) * DD + d] = hbuf[row * 65 + dl];
    }
}

extern "C" void kernel_launch(void* const* d_in, const int* in_sizes, int n_in,
                              void* d_out, int out_size, void* d_ws, size_t ws_size,
                              hipStream_t stream)
{
    const float* state = (const float*)d_in[0];
    const float* Wih   = (const float*)d_in[1];
    const float* Whh   = (const float*)d_in[2];
    const float* bih   = (const float*)d_in[3];
    const float* bhh   = (const float*)d_in[4];
    const float* bc    = (const float*)d_in[5];
    const int*   rec   = (const int*)d_in[6];

    char* ws = (char*)d_ws;
    float*    spart = (float*)ws;                   // 2 KB (8 shards x 64 t)
    unsigned* bar   = (unsigned*)(ws + 2048);       // 4 KB
    f16*   ApB   = (f16*)(ws + 2048 + 4096);        // 3 x 1.57 MB
    f16*   Wp0   = ApB + 3 * APCNT;                 // 6.29 MB
    f16*   Wp1   = Wp0 + WPCNT;                     // 6.29 MB
    float* out   = (float*)d_out;

    hipMemsetAsync(ws, 0, 2048 + 4096, stream);     // spart + barrier state
    // rec==0 robustness: output = state if no iteration runs
    hipMemcpyAsync(out, state, (size_t)NELEM * sizeof(float),
                   hipMemcpyDeviceToDevice, stream);

    conv_w<<<dim3(NSTRIPS * KSTEPS * 64 / 256), 256, 0, stream>>>(Wih, Whh, Wp0, Wp1);
    conv_a<<<dim3(MSTRIPS * KSTEPS * 64 / 256), 256, 0, stream>>>(state, ApB);

    gru_persist<<<dim3(NBLK), dim3(256), 0, stream>>>(
        ApB, Wp0, Wp1, bih, bhh, out, spart, bc, rec, bar);
}

// Round 7
// 945.144 us; speedup vs baseline: 10.5886x; 1.1638x over previous
//
#include <hip/hip_runtime.h>
#include <math.h>
#include <stdint.h>

// Problem constants
#define DD 500
#define BB 512
// Permuted N layout: slab s (0..63) owns cols [32s, 32s+32) = [r|z|i_n|h_n]
// for d in [8s, 8s+8).  col 32s + 8g + dd  <->  gate g of d = 8s+dd.
// r/z cols hold x@(Wih+Whh) for t>=1 (x==h); t=0 uses Wp0 (Wih only in r/z).
// K = 1536 split-precision: [Ah(512) | Al(512) | Ah(512)] x [Wh | Wh | Wl].
#define NSTRIPS 64     // n-strips (slabs) of 32
#define MSTRIPS 16     // m-strips of 32
#define KSTEPS  96     // ksteps of 16
#define NELEM (BB*DD)
// Persistent grid: 16 row-groups x 8 col-groups = 128 blocks.
// Block = 32 rows x 256 cols (8 slabs) x full K. bid%8 = col-group (= XCD
// under round-robin dispatch -> each XCD's L2 serves ONE 786KB Wp slice).
#define GM 16
#define GN 8
#define NBLK 128
#define HSTRIDE 2048   // floats per (block, hist slot): 32 rows x 64 d

typedef _Float16 f16;
typedef _Float16 f16x8 __attribute__((ext_vector_type(8)));
typedef float    f32x16 __attribute__((ext_vector_type(16)));

#define APCNT ((size_t)MSTRIPS * KSTEPS * 64 * 8)   // f16 per Ap buffer
#define WPCNT ((size_t)NSTRIPS * KSTEPS * 64 * 8)   // f16 per Wp buffer

// Fragment-order layout (both Ap and Wp):
//   elem(strip, kstep, ln, j)  at  ((strip*KSTEPS + kstep)*64 + ln)*8 + j
//   maps to  row = strip*32 + (ln&31),  k = kstep*16 + (ln>>5)*8 + j
// which is exactly the mfma_f32_32x32x16_f16 A/B operand layout.

// ---------------------------------------------------------------------------
// Device-scope (cross-XCD coherent) access helpers: relaxed AGENT atomics.
// sc-flagged, served at the Infinity Cache; no cache-wide maintenance ops.
// ---------------------------------------------------------------------------
__device__ __forceinline__ float aload_f32(const float* p) {
    return __hip_atomic_load(p, __ATOMIC_RELAXED, __HIP_MEMORY_SCOPE_AGENT);
}
__device__ __forceinline__ void astore_u64(unsigned long long* p,
                                           unsigned long long v) {
    __hip_atomic_store(p, v, __ATOMIC_RELAXED, __HIP_MEMORY_SCOPE_AGENT);
}
__device__ __forceinline__ uint4 aload16(const f16* p) {   // 16B via 2x8B
    const unsigned long long* q = (const unsigned long long*)p;
    unsigned long long a = __hip_atomic_load(q,     __ATOMIC_RELAXED,
                                             __HIP_MEMORY_SCOPE_AGENT);
    unsigned long long b = __hip_atomic_load(q + 1, __ATOMIC_RELAXED,
                                             __HIP_MEMORY_SCOPE_AGENT);
    uint4 r;
    r.x = (unsigned)a;  r.y = (unsigned)(a >> 32);
    r.z = (unsigned)b;  r.w = (unsigned)(b >> 32);
    return r;
}

// ---------------------------------------------------------------------------
// Wp0 (t=0) and Wp1 (t>=1), frag order, PERMUTED cols. k-blocks: [Wh|Wh|Wl].
// ---------------------------------------------------------------------------
__global__ __launch_bounds__(256) void conv_w(const float* __restrict__ Wih,
                                              const float* __restrict__ Whh,
                                              f16* __restrict__ Wp0,
                                              f16* __restrict__ Wp1)
{
    int p = blockIdx.x * 256 + threadIdx.x;    // (strip, kstep, ln)
    const int ln = p & 63; p >>= 6;
    const int kstep = p % KSTEPS;
    const int strip = p / KSTEPS;              // slab s, 0..63
    const int q = ln & 31;                     // col within slab
    const int g = q >> 3;                      // 0 r, 1 z, 2 i_n, 3 h_n
    const int d = strip * 8 + (q & 7);         // 0..511
    const int kb0 = kstep * 16 + (ln >> 5) * 8;
    const int blk = kb0 >> 9, bk0 = kb0 & 511;
    const float* pih = 0;
    const float* phh = 0;
    if (d < DD) {
        if (g == 0)      { pih = Wih + (size_t)d * DD;
                           phh = Whh + (size_t)d * DD; }
        else if (g == 1) { pih = Wih + (size_t)(500 + d) * DD;
                           phh = Whh + (size_t)(500 + d) * DD; }
        else if (g == 2) { pih = Wih + (size_t)(1000 + d) * DD; }
        else             { phh = Whh + (size_t)(1000 + d) * DD; }
    }
    f16 o0[8], o1[8];
    #pragma unroll
    for (int j = 0; j < 8; ++j) {
        const int bk = bk0 + j;
        float vi = 0.f, vh = 0.f;
        if (bk < DD) {
            if (pih) vi = pih[bk];
            if (phh) vh = phh[bk];
        }
        const float v0 = (g == 3) ? vh : vi;           // Wp0 value
        const float v1 = (g <= 1) ? (vi + vh) : v0;    // Wp1 value
        f16 h0 = (f16)v0;
        f16 h1 = (f16)v1;
        o0[j] = (blk == 2) ? (f16)(v0 - (float)h0) : h0;
        o1[j] = (blk == 2) ? (f16)(v1 - (float)h1) : h1;
    }
    const size_t off = ((size_t)(strip * KSTEPS + kstep) * 64 + ln) * 8;
    *(uint4*)(Wp0 + off) = *(uint4*)o0;
    *(uint4*)(Wp1 + off) = *(uint4*)o1;
}

// ---------------------------------------------------------------------------
// Ap buffer 0 (frag order) from initial state. k-blocks: [Ah | Al | Ah]
// ---------------------------------------------------------------------------
__global__ __launch_bounds__(256) void conv_a(const float* __restrict__ S,
                                              f16* __restrict__ Ap)
{
    int p = blockIdx.x * 256 + threadIdx.x;    // (mstrip, kstep, ln)
    const int ln = p & 63; p >>= 6;
    const int kstep = p % KSTEPS;
    const int strip = p / KSTEPS;              // 0..15
    const int b = strip * 32 + (ln & 31);
    const int kb0 = kstep * 16 + (ln >> 5) * 8;
    const int blk = kb0 >> 9, bk0 = kb0 & 511;
    f16 out[8];
    #pragma unroll
    for (int j = 0; j < 8; ++j) {
        const int bk = bk0 + j;
        float v = (bk < DD) ? S[(size_t)b * DD + bk] : 0.f;
        f16 hi = (f16)v;
        out[j] = (blk == 1) ? (f16)(v - (float)hi) : hi;
    }
    *(uint4*)(Ap + ((size_t)(strip * KSTEPS + kstep) * 64 + ln) * 8) = *(uint4*)out;
}

// ---------------------------------------------------------------------------
// Device-wide two-level barrier (used once per 8-iter WINDOW only).
// bar[g*16] g=0..15 group counters (64B apart, 8 blocks each), bar[512] root
// (16 arrivals), bar[528] generation. Monotone, relaxed atomics only.
// __syncthreads() (s_waitcnt vmcnt(0)) drains each wave's device-scope
// stores before thread 0 arrives.
// ---------------------------------------------------------------------------
__device__ __forceinline__ void grid_sync(unsigned* bar, unsigned e)
{
    __syncthreads();
    if (threadIdx.x == 0) {
        unsigned* gcnt = bar + ((blockIdx.x >> 3) << 4);
        unsigned* root = bar + 512;
        unsigned* gen  = bar + 528;
        unsigned a = __hip_atomic_fetch_add(gcnt, 1u, __ATOMIC_RELAXED,
                                            __HIP_MEMORY_SCOPE_AGENT);
        if (a == e * 8u + 7u) {
            unsigned r = __hip_atomic_fetch_add(root, 1u, __ATOMIC_RELAXED,
                                                __HIP_MEMORY_SCOPE_AGENT);
            if (r == e * 16u + 15u) {
                __hip_atomic_store(gen, e + 1u, __ATOMIC_RELAXED,
                                   __HIP_MEMORY_SCOPE_AGENT);
            } else {
                while (__hip_atomic_load(gen, __ATOMIC_RELAXED,
                                         __HIP_MEMORY_SCOPE_AGENT) <= e)
                    __builtin_amdgcn_s_sleep(1);
            }
        } else {
            while (__hip_atomic_load(gen, __ATOMIC_RELAXED,
                                     __HIP_MEMORY_SCOPE_AGENT) <= e)
                __builtin_amdgcn_s_sleep(1);
        }
    }
    __syncthreads();
}

// ---------------------------------------------------------------------------
// Persistent fused kernel, speculative break:
//   per-iteration sync = PER-GROUP monotone counter (8 arrivals: the only
//   data dependence is Ap rows [32mg..32mg+32) produced by blocks (mg,0..7));
//   grid-wide sync only every 8 iterations to scan the window's spart sums;
//   h history ring (8 deep, block-private, normal cached global) provides
//   the latched output h(t*) when the break fired inside the window.
// GEMM: 16-deep B register rings (lookahead ~450cyc > L2 lat) + 2-quarter-
// ahead A staging (lookahead ~900cyc >= MALL lat) into 2x24KB LDS dbuf.
// ---------------------------------------------------------------------------
__global__ __launch_bounds__(256, 1) void gru_persist(
    f16* __restrict__ ApB,                 // 2 buffers of APCNT
    const f16* __restrict__ Wp0, const f16* __restrict__ Wp1,
    const float* __restrict__ bih, const float* __restrict__ bhh,
    float* __restrict__ out, float* __restrict__ spart,  // [8][64] stride 64
    const float* __restrict__ bc, const int* __restrict__ rec,
    unsigned* __restrict__ bar, unsigned* __restrict__ garr,
    float* __restrict__ hist)
{
    const int bid = blockIdx.x;
    const int tid = threadIdx.x;
    const int rounds = min(64, rec[0]);
    if (rounds <= 0) return;               // uniform: no barriers entered
    const float thr = bc[0] * (float)NELEM;

    const int cg = bid & 7;                // col-group (d base = 64*cg)
    const int mg = bid >> 3;               // row-group = m-strip 0..15
    const int wv = tid >> 6, ln = tid & 63;
    const int sb0 = cg * 8 + 2 * wv, sb1 = sb0 + 1;    // this wave's slabs

    // 48 KB region: A double-buffer (2 x 24 KB) during gemm, Ct (36 KB) after
    __shared__ __align__(16) char smem[49152];
    f16*   Abuf0 = (f16*)smem;
    f16*   Abuf1 = (f16*)(smem + 24576);
    float* Ct    = (float*)smem;           // [row][sl][g][dd] = [32][8][4][9]
    __shared__ float hbuf[32 * 65];        // block-owned h, +1 pad
    __shared__ float red[4];
    __shared__ int   trig;

    f16* bufs0 = ApB;
    f16* bufs1 = ApB + APCNT;
    unsigned* gptr = garr + mg * 16;       // group counter (own 64B line)
    unsigned wep = 0;                      // grid-sync episode

    for (int t = 0; t < rounds; ++t) {
        const f16* Wb   = (t == 0) ? Wp0 : Wp1;
        const f16* Bp0  = Wb + (size_t)sb0 * KSTEPS * 512 + (size_t)ln * 8;
        const f16* Bp1  = Wb + (size_t)sb1 * KSTEPS * 512 + (size_t)ln * 8;
        const f16* Asrc = ((t & 1) ? bufs1 : bufs0) + (size_t)mg * KSTEPS * 512;
        f16*       Apw  = ((t & 1) ? bufs0 : bufs1);   // EW writes other buf

        // B ring prefill (L2-resident, independent of Ap -> before the wait)
        uint4 rB0[16], rB1[16];
        #pragma unroll
        for (int i = 0; i < 16; ++i) {
            rB0[i] = *(const uint4*)(Bp0 + (size_t)i * 512);
            rB1[i] = *(const uint4*)(Bp1 + (size_t)i * 512);
        }
        // group wait: all 8 producers of our A rows finished EW(t-1)
        if (t > 0) {
            if (tid == 0) {
                while (__hip_atomic_load(gptr, __ATOMIC_RELAXED,
                                         __HIP_MEMORY_SCOPE_AGENT)
                       < 8u * (unsigned)t)
                    __builtin_amdgcn_s_sleep(1);
            }
            __syncthreads();
        }

        // A-stage prologue: quarters 0,1 in flight; write q0; sync
        uint4 s0[6], s1[6];
        #pragma unroll
        for (int i = 0; i < 6; ++i)
            s0[i] = aload16(Asrc + (size_t)(tid + 256 * i) * 8);
        #pragma unroll
        for (int i = 0; i < 6; ++i)
            s1[i] = aload16(Asrc + 12288 + (size_t)(tid + 256 * i) * 8);
        #pragma unroll
        for (int i = 0; i < 6; ++i)
            *(uint4*)(Abuf0 + (size_t)(tid + 256 * i) * 8) = s0[i];
        __syncthreads();

        f32x16 acc0 = {}, acc1 = {};
        #pragma unroll
        for (int kq = 0; kq < 4; ++kq) {
            if (kq < 3) {                  // write quarter kq+1 to other buf
                f16* Aw = (kq & 1) ? Abuf0 : Abuf1;
                #pragma unroll
                for (int i = 0; i < 6; ++i)
                    *(uint4*)(Aw + (size_t)(tid + 256 * i) * 8)
                        = ((kq & 1) == 0) ? s1[i] : s0[i];
            }
            if (kq < 2) {                  // issue loads for quarter kq+2
                #pragma unroll
                for (int i = 0; i < 6; ++i) {
                    uint4 v = aload16(Asrc + (size_t)(kq + 2) * 12288
                                           + (size_t)(tid + 256 * i) * 8);
                    if ((kq & 1) == 0) s0[i] = v; else s1[i] = v;
                }
            }
            const f16* Ab = (kq & 1) ? Abuf1 : Abuf0;
            #pragma unroll
            for (int k2 = 0; k2 < 24; ++k2) {
                const int ks = kq * 24 + k2;           // compile-time
                f16x8 a  = *(const f16x8*)(Ab + (size_t)(k2 * 64 + ln) * 8);
                acc0 = __builtin_amdgcn_mfma_f32_32x32x16_f16(
                           a, *(f16x8*)&rB0[ks & 15], acc0, 0, 0, 0);
                acc1 = __builtin_amdgcn_mfma_f32_32x32x16_f16(
                           a, *(f16x8*)&rB1[ks & 15], acc1, 0, 0, 0);
                if (ks < 80) {             // refill 16 ksteps ahead
                    rB0[ks & 15] = *(const uint4*)(Bp0 + (size_t)(ks + 16) * 512);
                    rB1[ks & 15] = *(const uint4*)(Bp1 + (size_t)(ks + 16) * 512);
                }
            }
            __syncthreads();
        }
        // C -> LDS. C/D layout: col=lane&31, row=(r&3)+8*(r>>2)+4*(lane>>5).
        // Ct addr = row*288 + sl*36 + g*9 + dd
        {
            const int q = ln & 31, g = q >> 3, dd = q & 7;
            const int sl0 = 2 * wv, sl1 = 2 * wv + 1;
            #pragma unroll
            for (int r = 0; r < 16; ++r) {
                const int row = (r & 3) + 8 * (r >> 2) + 4 * (ln >> 5);
                Ct[row * 288 + sl0 * 36 + g * 9 + dd] = acc0[r];
                Ct[row * 288 + sl1 * 36 + g * 9 + dd] = acc1[r];
            }
        }
        __syncthreads();

        // ---------------- EW phase (all in-block) -------------------------
        float* hw = hist + ((size_t)bid * 8 + (size_t)(t & 7)) * HSTRIDE;
        float psum = 0.0f;
        #pragma unroll
        for (int i = 0; i < 8; ++i) {
            const int idx = i * 256 + tid;     // 2048 (row, dl) pairs
            const int row = idx >> 6, dl = idx & 63;
            const int d = cg * 64 + dl;
            const int sl = dl >> 3, dd = dl & 7;
            float hnew = 0.0f;
            if (d < DD) {
                const float* cb = &Ct[row * 288 + sl * 36 + dd];
                float cr = cb[0], cz = cb[9], cin = cb[18], chn = cb[27];
                float r = 1.0f / (1.0f + expf(-(cr + bih[d] + bhh[d])));
                float z = 1.0f / (1.0f + expf(-(cz + bih[500 + d] + bhh[500 + d])));
                float inn = cin + bih[1000 + d];
                float hn  = bhh[1000 + d];
                float hp  = 0.0f;
                if (t > 0) { hn += chn; hp = hbuf[row * 65 + dl]; }
                float n = tanhf(inn + r * hn);
                hnew = (1.0f - z) * n + z * hp;
                psum += hnew;
            }
            hbuf[row * 65 + dl] = hnew;        // same-thread slot: race-free
            hw[idx] = hnew;                    // history ring (block-private)
        }
        // block reduce psum -> spart shard cg
        #pragma unroll
        for (int off = 32; off > 0; off >>= 1) psum += __shfl_down(psum, off, 64);
        if (ln == 0) red[wv] = psum;
        __syncthreads();                        // also orders hbuf before pack
        if (tid == 0) {
            float v = red[0] + red[1] + red[2] + red[3];
            __hip_atomic_fetch_add(&spart[(size_t)cg * 64 + t], v,
                                   __ATOMIC_RELAXED, __HIP_MEMORY_SCOPE_AGENT);
        }
        // pack Ap (16B per (row, d-octet, k-block)): hi @d, lo @512+d, hi @1024+d
        {
            const int lm = tid & 31, oct = tid >> 5;   // row, d-octet
            union { f16 a[8]; unsigned long long u[2]; } hiU, loU;
            #pragma unroll
            for (int j = 0; j < 8; ++j) {
                float v = hbuf[lm * 65 + oct * 8 + j];
                f16 hi = (f16)v;
                hiU.a[j] = hi;
                loU.a[j] = (f16)(v - (float)hi);
            }
            const int d0 = cg * 64 + oct * 8;
            #pragma unroll
            for (int kb = 0; kb < 3; ++kb) {
                const int k0 = kb * 512 + d0;
                const int kstep = k0 >> 4, half = (k0 >> 3) & 1;
                unsigned long long* dst = (unsigned long long*)
                    (Apw + ((size_t)(mg * KSTEPS + kstep) * 64 + half * 32 + lm) * 8);
                astore_u64(dst,     (kb == 1) ? loU.u[0] : hiU.u[0]);
                astore_u64(dst + 1, (kb == 1) ? loU.u[1] : hiU.u[1]);
            }
        }
        __syncthreads();                       // drain all waves' sc1 stores
        if (tid == 0)
            __hip_atomic_fetch_add(gptr, 1u, __ATOMIC_RELAXED,
                                   __HIP_MEMORY_SCOPE_AGENT);

        // -------- window boundary: grid sync + break scan -----------------
        if (((t & 7) == 7) || (t == rounds - 1)) {
            grid_sync(bar, wep++);             // all spart(t' <= t) visible
            if (tid < 64) {                    // wave 0 scans the window
                const int cgl = tid & 7, ti = tid >> 3;
                const int tt = (t & ~7) + ti;
                float v = 0.f;
                if (tt <= t)
                    v = aload_f32(&spart[(size_t)cgl * 64 + tt]);
                v += __shfl_xor(v, 1, 64);
                v += __shfl_xor(v, 2, 64);
                v += __shfl_xor(v, 4, 64);
                bool hit = ((tid & 7) == 0) && (tt <= t) && (v > thr);
                unsigned long long m = __ballot(hit);
                if (tid == 0)
                    trig = m ? (int)((__ffsll((long long)m) - 1) >> 3) : -1;
            }
            __syncthreads();
            const int w0 = trig;
            if (w0 >= 0) {                     // break fired at ts (uniform)
                const int ts = (t & ~7) + w0;
                const float* hs = hist
                    + ((size_t)bid * 8 + (size_t)(ts & 7)) * HSTRIDE;
                #pragma unroll
                for (int i = 0; i < 8; ++i) {
                    const int idx = i * 256 + tid;
                    const int row = idx >> 6, dl = idx & 63;
                    const int d = cg * 64 + dl;
                    if (d < DD)
                        out[(size_t)(mg * 32 + row) * DD + d] = hs[idx];
                }
                return;
            }
        }
    }

    // no trigger: final output from block-owned h slice
    #pragma unroll
    for (int i = 0; i < 8; ++i) {
        const int idx = i * 256 + tid;
        const int row = idx >> 6, dl = idx & 63;
        const int d = cg * 64 + dl;
        if (d < DD)
            out[(size_t)(mg * 32 + row) * DD + d] = hbuf[row * 65 + dl];
    }
}

extern "C" void kernel_launch(void* const* d_in, const int* in_sizes, int n_in,
                              void* d_out, int out_size, void* d_ws, size_t ws_size,
                              hipStream_t stream)
{
    const float* state = (const float*)d_in[0];
    const float* Wih   = (const float*)d_in[1];
    const float* Whh   = (const float*)d_in[2];
    const float* bih   = (const float*)d_in[3];
    const float* bhh   = (const float*)d_in[4];
    const float* bc    = (const float*)d_in[5];
    const int*   rec   = (const int*)d_in[6];

    char* ws = (char*)d_ws;
    float*    spart = (float*)ws;                   // 2 KB (8 shards x 64 t)
    unsigned* bar   = (unsigned*)(ws + 2048);       // 4 KB
    unsigned* garr  = (unsigned*)(ws + 6144);       // 1 KB (16 x 64B)
    f16*   ApB   = (f16*)(ws + 8192);               // 2 x 1.57 MB
    f16*   Wp0   = ApB + 2 * APCNT;                 // 6.29 MB
    f16*   Wp1   = Wp0 + WPCNT;                     // 6.29 MB
    float* hist  = (float*)(Wp1 + WPCNT);           // 8.39 MB (128x8x2048 f32)
    float* out   = (float*)d_out;

    hipMemsetAsync(ws, 0, 8192, stream);            // spart + bar + garr
    // rec==0 robustness: output = state if no iteration runs
    hipMemcpyAsync(out, state, (size_t)NELEM * sizeof(float),
                   hipMemcpyDeviceToDevice, stream);

    conv_w<<<dim3(NSTRIPS * KSTEPS * 64 / 256), 256, 0, stream>>>(Wih, Whh, Wp0, Wp1);
    conv_a<<<dim3(MSTRIPS * KSTEPS * 64 / 256), 256, 0, stream>>>(state, ApB);

    gru_persist<<<dim3(NBLK), dim3(256), 0, stream>>>(
        ApB, Wp0, Wp1, bih, bhh, out, spart, bc, rec, bar, garr, hist);
}

// Round 9
// 909.290 us; speedup vs baseline: 11.0061x; 1.0394x over previous
//
#include <hip/hip_runtime.h>
#include <math.h>
#include <stdint.h>

// Problem constants
#define DD 500
#define BB 512
// Permuted N layout: slab s (0..63) owns cols [32s, 32s+32) = [r|z|i_n|h_n]
// for d in [8s, 8s+8).  col 32s + 8g + dd  <->  gate g of d = 8s+dd.
// r/z cols hold x@(Wih+Whh) for t>=1 (x==h); t=0 uses Wp0 (Wih only in r/z).
// K = 1536 split-precision: [Ah(512) | Al(512) | Ah(512)] x [Wh | Wh | Wl].
#define NSTRIPS 64     // n-strips (slabs) of 32
#define MSTRIPS 16     // m-strips of 32
#define KSTEPS  96     // ksteps of 16
#define NELEM (BB*DD)
// Persistent grid: 16 row-groups x 8 col-groups = 128 blocks.
// Block = 32 rows x 256 cols (8 slabs) x full K. bid%8 = col-group (= XCD
// under round-robin dispatch -> each XCD's L2 serves ONE 786KB Wp slice).
#define GM 16
#define GN 8
#define NBLK 128
#define HSTRIDE 2048   // floats per (block, hist slot): 32 rows x 64 d

typedef _Float16 f16;
typedef _Float16 f16x8 __attribute__((ext_vector_type(8)));
typedef float    f32x16 __attribute__((ext_vector_type(16)));

#define APCNT ((size_t)MSTRIPS * KSTEPS * 64 * 8)   // f16 per Ap buffer
#define WPCNT ((size_t)NSTRIPS * KSTEPS * 64 * 8)   // f16 per Wp buffer

// Fragment-order layout (both Ap and Wp):
//   elem(strip, kstep, ln, j)  at  ((strip*KSTEPS + kstep)*64 + ln)*8 + j
//   maps to  row = strip*32 + (ln&31),  k = kstep*16 + (ln>>5)*8 + j
// which is exactly the mfma_f32_32x32x16_f16 A/B operand layout.

// ---------------------------------------------------------------------------
// Device-scope (cross-XCD coherent) access helpers: relaxed AGENT atomics.
// sc-flagged, served at the device coherence point; no cache-wide ops.
// ---------------------------------------------------------------------------
__device__ __forceinline__ float aload_f32(const float* p) {
    return __hip_atomic_load(p, __ATOMIC_RELAXED, __HIP_MEMORY_SCOPE_AGENT);
}
__device__ __forceinline__ void astore_u64(unsigned long long* p,
                                           unsigned long long v) {
    __hip_atomic_store(p, v, __ATOMIC_RELAXED, __HIP_MEMORY_SCOPE_AGENT);
}
__device__ __forceinline__ uint4 aload16(const f16* p) {   // 16B via 2x8B
    const unsigned long long* q = (const unsigned long long*)p;
    unsigned long long a = __hip_atomic_load(q,     __ATOMIC_RELAXED,
                                             __HIP_MEMORY_SCOPE_AGENT);
    unsigned long long b = __hip_atomic_load(q + 1, __ATOMIC_RELAXED,
                                             __HIP_MEMORY_SCOPE_AGENT);
    uint4 r;
    r.x = (unsigned)a;  r.y = (unsigned)(a >> 32);
    r.z = (unsigned)b;  r.w = (unsigned)(b >> 32);
    return r;
}

// fast sigmoid via hardware v_exp (2^x): rel err ~1e-6, safe at our tolerance
__device__ __forceinline__ float fsigmoid(float x) {
    return 1.0f / (1.0f + __expf(-x));
}
__device__ __forceinline__ float ftanh(float x) {
    return 2.0f / (1.0f + __expf(-2.0f * x)) - 1.0f;
}

// ---------------------------------------------------------------------------
// Wp0 (t=0) and Wp1 (t>=1), frag order, PERMUTED cols. k-blocks: [Wh|Wh|Wl].
// ---------------------------------------------------------------------------
__global__ __launch_bounds__(256) void conv_w(const float* __restrict__ Wih,
                                              const float* __restrict__ Whh,
                                              f16* __restrict__ Wp0,
                                              f16* __restrict__ Wp1)
{
    int p = blockIdx.x * 256 + threadIdx.x;    // (strip, kstep, ln)
    const int ln = p & 63; p >>= 6;
    const int kstep = p % KSTEPS;
    const int strip = p / KSTEPS;              // slab s, 0..63
    const int q = ln & 31;                     // col within slab
    const int g = q >> 3;                      // 0 r, 1 z, 2 i_n, 3 h_n
    const int d = strip * 8 + (q & 7);         // 0..511
    const int kb0 = kstep * 16 + (ln >> 5) * 8;
    const int blk = kb0 >> 9, bk0 = kb0 & 511;
    const float* pih = 0;
    const float* phh = 0;
    if (d < DD) {
        if (g == 0)      { pih = Wih + (size_t)d * DD;
                           phh = Whh + (size_t)d * DD; }
        else if (g == 1) { pih = Wih + (size_t)(500 + d) * DD;
                           phh = Whh + (size_t)(500 + d) * DD; }
        else if (g == 2) { pih = Wih + (size_t)(1000 + d) * DD; }
        else             { phh = Whh + (size_t)(1000 + d) * DD; }
    }
    f16 o0[8], o1[8];
    #pragma unroll
    for (int j = 0; j < 8; ++j) {
        const int bk = bk0 + j;
        float vi = 0.f, vh = 0.f;
        if (bk < DD) {
            if (pih) vi = pih[bk];
            if (phh) vh = phh[bk];
        }
        const float v0 = (g == 3) ? vh : vi;           // Wp0 value
        const float v1 = (g <= 1) ? (vi + vh) : v0;    // Wp1 value
        f16 h0 = (f16)v0;
        f16 h1 = (f16)v1;
        o0[j] = (blk == 2) ? (f16)(v0 - (float)h0) : h0;
        o1[j] = (blk == 2) ? (f16)(v1 - (float)h1) : h1;
    }
    const size_t off = ((size_t)(strip * KSTEPS + kstep) * 64 + ln) * 8;
    *(uint4*)(Wp0 + off) = *(uint4*)o0;
    *(uint4*)(Wp1 + off) = *(uint4*)o1;
}

// ---------------------------------------------------------------------------
// Ap buffer 0 (frag order) from initial state. k-blocks: [Ah | Al | Ah]
// ---------------------------------------------------------------------------
__global__ __launch_bounds__(256) void conv_a(const float* __restrict__ S,
                                              f16* __restrict__ Ap)
{
    int p = blockIdx.x * 256 + threadIdx.x;    // (mstrip, kstep, ln)
    const int ln = p & 63; p >>= 6;
    const int kstep = p % KSTEPS;
    const int strip = p / KSTEPS;              // 0..15
    const int b = strip * 32 + (ln & 31);
    const int kb0 = kstep * 16 + (ln >> 5) * 8;
    const int blk = kb0 >> 9, bk0 = kb0 & 511;
    f16 out[8];
    #pragma unroll
    for (int j = 0; j < 8; ++j) {
        const int bk = bk0 + j;
        float v = (bk < DD) ? S[(size_t)b * DD + bk] : 0.f;
        f16 hi = (f16)v;
        out[j] = (blk == 1) ? (f16)(v - (float)hi) : hi;
    }
    *(uint4*)(Ap + ((size_t)(strip * KSTEPS + kstep) * 64 + ln) * 8) = *(uint4*)out;
}

// ---------------------------------------------------------------------------
// Device-wide two-level barrier (used once per 8-iter WINDOW only).
// bar[g*16] g=0..15 group counters (64B apart, 8 blocks each), bar[512] root
// (16 arrivals), bar[528] generation. Monotone, relaxed atomics only.
// ---------------------------------------------------------------------------
__device__ __forceinline__ void grid_sync(unsigned* bar, unsigned e)
{
    __syncthreads();
    if (threadIdx.x == 0) {
        unsigned* gcnt = bar + ((blockIdx.x >> 3) << 4);
        unsigned* root = bar + 512;
        unsigned* gen  = bar + 528;
        unsigned a = __hip_atomic_fetch_add(gcnt, 1u, __ATOMIC_RELAXED,
                                            __HIP_MEMORY_SCOPE_AGENT);
        if (a == e * 8u + 7u) {
            unsigned r = __hip_atomic_fetch_add(root, 1u, __ATOMIC_RELAXED,
                                                __HIP_MEMORY_SCOPE_AGENT);
            if (r == e * 16u + 15u) {
                __hip_atomic_store(gen, e + 1u, __ATOMIC_RELAXED,
                                   __HIP_MEMORY_SCOPE_AGENT);
            } else {
                while (__hip_atomic_load(gen, __ATOMIC_RELAXED,
                                         __HIP_MEMORY_SCOPE_AGENT) <= e)
                    __builtin_amdgcn_s_sleep(1);
            }
        } else {
            while (__hip_atomic_load(gen, __ATOMIC_RELAXED,
                                     __HIP_MEMORY_SCOPE_AGENT) <= e)
                __builtin_amdgcn_s_sleep(1);
        }
    }
    __syncthreads();
}

// ---------------------------------------------------------------------------
// Persistent fused kernel, speculative break (structure proven in R7):
//   per-iter sync = per-row-group monotone counter (8 arrivals);
//   grid-wide sync every 8 iters scans spart; 8-deep h history ring gives
//   the latched output if the break fired inside the window.
// GEMM: B rings 12-deep x 2 (96 VGPRs, sized to STAY RESIDENT; lookahead
// 192cyc ~ L2 latency) + 2-quarter-ahead A staging into 2x24KB LDS dbuf.
// ---------------------------------------------------------------------------
__global__ __launch_bounds__(256, 1) void gru_persist(
    f16* __restrict__ ApB,                 // 2 buffers of APCNT
    const f16* __restrict__ Wp0, const f16* __restrict__ Wp1,
    const float* __restrict__ bih, const float* __restrict__ bhh,
    float* __restrict__ out, float* __restrict__ spart,  // [8][64] stride 64
    const float* __restrict__ bc, const int* __restrict__ rec,
    unsigned* __restrict__ bar, unsigned* __restrict__ garr,
    float* __restrict__ hist)
{
    const int bid = blockIdx.x;
    const int tid = threadIdx.x;
    const int rounds = min(64, rec[0]);
    if (rounds <= 0) return;               // uniform: no barriers entered
    const float thr = bc[0] * (float)NELEM;

    const int cg = bid & 7;                // col-group (d base = 64*cg)
    const int mg = bid >> 3;               // row-group = m-strip 0..15
    const int wv = tid >> 6, ln = tid & 63;
    const int sb0 = cg * 8 + 2 * wv, sb1 = sb0 + 1;    // this wave's slabs

    // 48 KB region: A double-buffer (2 x 24 KB) during gemm, Ct (36 KB) after
    __shared__ __align__(16) char smem[49152];
    f16*   Abuf0 = (f16*)smem;
    f16*   Abuf1 = (f16*)(smem + 24576);
    float* Ct    = (float*)smem;           // [row][sl][g][dd] = [32][8][4][9]
    __shared__ float hbuf[32 * 65];        // block-owned h, +1 pad
    __shared__ float red[4];
    __shared__ int   trig;

    f16* bufs0 = ApB;
    f16* bufs1 = ApB + APCNT;
    unsigned* gptr = garr + mg * 16;       // group counter (own 64B line)
    unsigned wep = 0;                      // grid-sync episode

    for (int t = 0; t < rounds; ++t) {
        const f16* Wb   = (t == 0) ? Wp0 : Wp1;
        const f16* Bp0  = Wb + (size_t)sb0 * KSTEPS * 512 + (size_t)ln * 8;
        const f16* Bp1  = Wb + (size_t)sb1 * KSTEPS * 512 + (size_t)ln * 8;
        const f16* Asrc = ((t & 1) ? bufs1 : bufs0) + (size_t)mg * KSTEPS * 512;
        f16*       Apw  = ((t & 1) ? bufs0 : bufs1);   // EW writes other buf

        // B ring prefill (L2-resident, independent of Ap -> before the wait)
        uint4 rB0[12], rB1[12];
        #pragma unroll
        for (int i = 0; i < 12; ++i) {
            rB0[i] = *(const uint4*)(Bp0 + (size_t)i * 512);
            rB1[i] = *(const uint4*)(Bp1 + (size_t)i * 512);
        }
        // group wait: all 8 producers of our A rows finished EW(t-1)
        if (t > 0) {
            if (tid == 0) {
                while (__hip_atomic_load(gptr, __ATOMIC_RELAXED,
                                         __HIP_MEMORY_SCOPE_AGENT)
                       < 8u * (unsigned)t)
                    __builtin_amdgcn_s_sleep(1);
            }
            __syncthreads();
        }

        // A-stage prologue: quarters 0,1 in flight; write q0; sync
        uint4 s0[6], s1[6];
        #pragma unroll
        for (int i = 0; i < 6; ++i)
            s0[i] = aload16(Asrc + (size_t)(tid + 256 * i) * 8);
        #pragma unroll
        for (int i = 0; i < 6; ++i)
            s1[i] = aload16(Asrc + 12288 + (size_t)(tid + 256 * i) * 8);
        #pragma unroll
        for (int i = 0; i < 6; ++i)
            *(uint4*)(Abuf0 + (size_t)(tid + 256 * i) * 8) = s0[i];
        __syncthreads();

        f32x16 acc0 = {}, acc1 = {};
        #pragma unroll
        for (int kq = 0; kq < 4; ++kq) {
            if (kq < 3) {                  // write quarter kq+1 to other buf
                f16* Aw = (kq & 1) ? Abuf0 : Abuf1;
                #pragma unroll
                for (int i = 0; i < 6; ++i)
                    *(uint4*)(Aw + (size_t)(tid + 256 * i) * 8)
                        = ((kq & 1) == 0) ? s1[i] : s0[i];
            }
            if (kq < 2) {                  // issue loads for quarter kq+2
                #pragma unroll
                for (int i = 0; i < 6; ++i) {
                    uint4 v = aload16(Asrc + (size_t)(kq + 2) * 12288
                                           + (size_t)(tid + 256 * i) * 8);
                    if ((kq & 1) == 0) s0[i] = v; else s1[i] = v;
                }
            }
            const f16* Ab = (kq & 1) ? Abuf1 : Abuf0;
            #pragma unroll
            for (int k2 = 0; k2 < 24; ++k2) {
                const int ks = kq * 24 + k2;           // compile-time
                f16x8 a  = *(const f16x8*)(Ab + (size_t)(k2 * 64 + ln) * 8);
                acc0 = __builtin_amdgcn_mfma_f32_32x32x16_f16(
                           a, *(f16x8*)&rB0[ks % 12], acc0, 0, 0, 0);
                acc1 = __builtin_amdgcn_mfma_f32_32x32x16_f16(
                           a, *(f16x8*)&rB1[ks % 12], acc1, 0, 0, 0);
                if (ks < 84) {             // refill 12 ksteps ahead
                    rB0[ks % 12] = *(const uint4*)(Bp0 + (size_t)(ks + 12) * 512);
                    rB1[ks % 12] = *(const uint4*)(Bp1 + (size_t)(ks + 12) * 512);
                }
            }
            __syncthreads();
        }
        // C -> LDS. C/D layout: col=lane&31, row=(r&3)+8*(r>>2)+4*(lane>>5).
        // Ct addr = row*288 + sl*36 + g*9 + dd
        {
            const int q = ln & 31, g = q >> 3, dd = q & 7;
            const int sl0 = 2 * wv, sl1 = 2 * wv + 1;
            #pragma unroll
            for (int r = 0; r < 16; ++r) {
                const int row = (r & 3) + 8 * (r >> 2) + 4 * (ln >> 5);
                Ct[row * 288 + sl0 * 36 + g * 9 + dd] = acc0[r];
                Ct[row * 288 + sl1 * 36 + g * 9 + dd] = acc1[r];
            }
        }
        __syncthreads();

        // ---------------- EW phase (all in-block) -------------------------
        float* hw = hist + ((size_t)bid * 8 + (size_t)(t & 7)) * HSTRIDE;
        float psum = 0.0f;
        #pragma unroll
        for (int i = 0; i < 8; ++i) {
            const int idx = i * 256 + tid;     // 2048 (row, dl) pairs
            const int row = idx >> 6, dl = idx & 63;
            const int d = cg * 64 + dl;
            const int sl = dl >> 3, dd = dl & 7;
            float hnew = 0.0f;
            if (d < DD) {
                const float* cb = &Ct[row * 288 + sl * 36 + dd];
                float cr = cb[0], cz = cb[9], cin = cb[18], chn = cb[27];
                float r = fsigmoid(cr + bih[d] + bhh[d]);
                float z = fsigmoid(cz + bih[500 + d] + bhh[500 + d]);
                float inn = cin + bih[1000 + d];
                float hn  = bhh[1000 + d];
                float hp  = 0.0f;
                if (t > 0) { hn += chn; hp = hbuf[row * 65 + dl]; }
                float n = ftanh(inn + r * hn);
                hnew = (1.0f - z) * n + z * hp;
                psum += hnew;
            }
            hbuf[row * 65 + dl] = hnew;        // same-thread slot: race-free
            hw[idx] = hnew;                    // history ring (block-private)
        }
        // block reduce psum -> spart shard cg
        #pragma unroll
        for (int off = 32; off > 0; off >>= 1) psum += __shfl_down(psum, off, 64);
        if (ln == 0) red[wv] = psum;
        __syncthreads();                        // also orders hbuf before pack
        if (tid == 0) {
            float v = red[0] + red[1] + red[2] + red[3];
            __hip_atomic_fetch_add(&spart[(size_t)cg * 64 + t], v,
                                   __ATOMIC_RELAXED, __HIP_MEMORY_SCOPE_AGENT);
        }
        // pack Ap (16B per (row, d-octet, k-block)): hi @d, lo @512+d, hi @1024+d
        {
            const int lm = tid & 31, oct = tid >> 5;   // row, d-octet
            union { f16 a[8]; unsigned long long u[2]; } hiU, loU;
            #pragma unroll
            for (int j = 0; j < 8; ++j) {
                float v = hbuf[lm * 65 + oct * 8 + j];
                f16 hi = (f16)v;
                hiU.a[j] = hi;
                loU.a[j] = (f16)(v - (float)hi);
            }
            const int d0 = cg * 64 + oct * 8;
            #pragma unroll
            for (int kb = 0; kb < 3; ++kb) {
                const int k0 = kb * 512 + d0;
                const int kstep = k0 >> 4, half = (k0 >> 3) & 1;
                unsigned long long* dst = (unsigned long long*)
                    (Apw + ((size_t)(mg * KSTEPS + kstep) * 64 + half * 32 + lm) * 8);
                astore_u64(dst,     (kb == 1) ? loU.u[0] : hiU.u[0]);
                astore_u64(dst + 1, (kb == 1) ? loU.u[1] : hiU.u[1]);
            }
        }
        __syncthreads();                       // drain all waves' sc1 stores
        if (tid == 0)
            __hip_atomic_fetch_add(gptr, 1u, __ATOMIC_RELAXED,
                                   __HIP_MEMORY_SCOPE_AGENT);

        // -------- window boundary: grid sync + break scan -----------------
        if (((t & 7) == 7) || (t == rounds - 1)) {
            grid_sync(bar, wep++);             // all spart(t' <= t) visible
            if (tid < 64) {                    // wave 0 scans the window
                const int cgl = tid & 7, ti = tid >> 3;
                const int tt = (t & ~7) + ti;
                float v = 0.f;
                if (tt <= t)
                    v = aload_f32(&spart[(size_t)cgl * 64 + tt]);
                v += __shfl_xor(v, 1, 64);
                v += __shfl_xor(v, 2, 64);
                v += __shfl_xor(v, 4, 64);
                bool hit = ((tid & 7) == 0) && (tt <= t) && (v > thr);
                unsigned long long m = __ballot(hit);
                if (tid == 0)
                    trig = m ? (int)((__ffsll((long long)m) - 1) >> 3) : -1;
            }
            __syncthreads();
            const int w0 = trig;
            if (w0 >= 0) {                     // break fired at ts (uniform)
                const int ts = (t & ~7) + w0;
                const float* hs = hist
                    + ((size_t)bid * 8 + (size_t)(ts & 7)) * HSTRIDE;
                #pragma unroll
                for (int i = 0; i < 8; ++i) {
                    const int idx = i * 256 + tid;
                    const int row = idx >> 6, dl = idx & 63;
                    const int d = cg * 64 + dl;
                    if (d < DD)
                        out[(size_t)(mg * 32 + row) * DD + d] = hs[idx];
                }
                return;
            }
        }
    }

    // no trigger: final output from block-owned h slice
    #pragma unroll
    for (int i = 0; i < 8; ++i) {
        const int idx = i * 256 + tid;
        const int row = idx >> 6, dl = idx & 63;
        const int d = cg * 64 + dl;
        if (d < DD)
            out[(size_t)(mg * 32 + row) * DD + d] = hbuf[row * 65 + dl];
    }
}

extern "C" void kernel_launch(void* const* d_in, const int* in_sizes, int n_in,
                              void* d_out, int out_size, void* d_ws, size_t ws_size,
                              hipStream_t stream)
{
    const float* state = (const float*)d_in[0];
    const float* Wih   = (const float*)d_in[1];
    const float* Whh   = (const float*)d_in[2];
    const float* bih   = (const float*)d_in[3];
    const float* bhh   = (const float*)d_in[4];
    const float* bc    = (const float*)d_in[5];
    const int*   rec   = (const int*)d_in[6];

    char* ws = (char*)d_ws;
    float*    spart = (float*)ws;                   // 2 KB (8 shards x 64 t)
    unsigned* bar   = (unsigned*)(ws + 2048);       // 4 KB
    unsigned* garr  = (unsigned*)(ws + 6144);       // 1 KB (16 x 64B)
    f16*   ApB   = (f16*)(ws + 8192);               // 2 x 1.57 MB
    f16*   Wp0   = ApB + 2 * APCNT;                 // 6.29 MB
    f16*   Wp1   = Wp0 + WPCNT;                     // 6.29 MB
    float* hist  = (float*)(Wp1 + WPCNT);           // 8.39 MB (128x8x2048 f32)
    float* out   = (float*)d_out;

    hipMemsetAsync(ws, 0, 8192, stream);            // spart + bar + garr
    // rec==0 robustness: output = state if no iteration runs
    hipMemcpyAsync(out, state, (size_t)NELEM * sizeof(float),
                   hipMemcpyDeviceToDevice, stream);

    conv_w<<<dim3(NSTRIPS * KSTEPS * 64 / 256), 256, 0, stream>>>(Wih, Whh, Wp0, Wp1);
    conv_a<<<dim3(MSTRIPS * KSTEPS * 64 / 256), 256, 0, stream>>>(state, ApB);

    gru_persist<<<dim3(NBLK), dim3(256), 0, stream>>>(
        ApB, Wp0, Wp1, bih, bhh, out, spart, bc, rec, bar, garr, hist);
}